// Round 3
// baseline (740.175 us; speedup 1.0000x reference)
//
#include <hip/hip_runtime.h>

static inline int ceil_div(int a, int b) { return (a + b - 1) / b; }

typedef __attribute__((ext_vector_type(8))) short short8;
typedef __attribute__((ext_vector_type(4))) float floatx4;

__device__ __forceinline__ unsigned short f2bf(float f) {
    unsigned int u = __float_as_uint(f);
    unsigned int r = (u + 0x7fffu + ((u >> 16) & 1u)) >> 16;
    return (unsigned short)r;
}
__device__ __forceinline__ float bf2f(unsigned short h) {
    return __uint_as_float(((unsigned int)h) << 16);
}

// ---------------- CSR scan ----------------
__global__ __launch_bounds__(1024) void scan1_k(const int* __restrict__ deg,
                                                int* __restrict__ excl,
                                                int* __restrict__ bsum, int Nv) {
    __shared__ int s[1024];
    int tid = threadIdx.x;
    int i = blockIdx.x * 1024 + tid;
    int v = (i < Nv) ? deg[i] : 0;
    s[tid] = v;
    __syncthreads();
    for (int off = 1; off < 1024; off <<= 1) {
        int t = (tid >= off) ? s[tid - off] : 0;
        __syncthreads();
        if (tid >= off) s[tid] += t;
        __syncthreads();
    }
    if (i < Nv) excl[i] = s[tid] - v;
    if (tid == 1023) bsum[blockIdx.x] = s[1023];
}

__global__ __launch_bounds__(64) void scan2_k(int* __restrict__ bsum, int nb) {
    __shared__ int s[64];
    int tid = threadIdx.x;
    int v = (tid < nb) ? bsum[tid] : 0;
    s[tid] = v;
    __syncthreads();
    for (int off = 1; off < 64; off <<= 1) {
        int t = (tid >= off) ? s[tid - off] : 0;
        __syncthreads();
        if (tid >= off) s[tid] += t;
        __syncthreads();
    }
    if (tid < nb) bsum[tid] = s[tid] - v;
}

__global__ __launch_bounds__(1024) void scan3_k(const int* __restrict__ excl,
                                                const int* __restrict__ bsum,
                                                const int* __restrict__ deg,
                                                int* __restrict__ rowptr,
                                                int* __restrict__ cursor, int Nv) {
    int i = blockIdx.x * 1024 + threadIdx.x;
    if (i < Nv) {
        int val = excl[i] + bsum[blockIdx.x];
        rowptr[i] = val;
        cursor[i] = val;
        if (i == Nv - 1) rowptr[Nv] = val + deg[i];
    }
}

__global__ __launch_bounds__(256) void fill_adj_k(const int* __restrict__ edges,
                                                  int* __restrict__ cursor,
                                                  int* __restrict__ adj, int E) {
    int e = blockIdx.x * blockDim.x + threadIdx.x;
    if (e < E) {
        int a = edges[2 * e], b = edges[2 * e + 1];
        adj[atomicAdd(&cursor[a], 1)] = b;
        adj[atomicAdd(&cursor[b], 1)] = a;
    }
}

// ---------------- fat prologue: count_deg | prep_w | prep_bwT | enc_proj ----------------
__global__ __launch_bounds__(256) void fatpre_k(const int* __restrict__ edges,
                                                int* __restrict__ deg, int E, int nE,
                                                const float* __restrict__ g0w0,
                                                const float* __restrict__ g0w1,
                                                const float* __restrict__ gw0,
                                                const float* __restrict__ gw1,
                                                unsigned short* __restrict__ Wt,
                                                const float* __restrict__ bw,
                                                unsigned short* __restrict__ bwT,
                                                const float* __restrict__ enc,
                                                float* __restrict__ encp, int B_) {
    int bid = blockIdx.x;
    int tid = threadIdx.x;
    if (bid < nE) {
        int e = bid * 256 + tid;
        if (e < E) {
            atomicAdd(&deg[edges[2 * e]], 1);
            atomicAdd(&deg[edges[2 * e + 1]], 1);
        }
    } else if (bid < nE + 16) {
        int lh = bid - nE;
        int l = lh >> 1, h = lh & 1;
        const float* src;
        if (l == 0) src = h ? g0w1 : g0w0;
        else src = (h ? gw1 : gw0) + (size_t)(l - 1) * 16384;
        unsigned short* dst = Wt + (size_t)lh * 16384;
        for (int idx = tid; idx < 16384; idx += 256) {
            int n = idx >> 7, k = idx & 127;
            dst[n * 128 + k] = f2bf(src[k * 128 + n]);
        }
    } else if (bid < nE + 46) {
        // bottleneck weight transpose+cast: bwT[n][k] = bf16(bw[k][n])
        int blk = bid - nE - 16;  // 0..29
        for (int idx = tid; idx < 16384; idx += 256) {
            int n = idx >> 7, kk = idx & 127;
            bwT[(size_t)n * 3840 + blk * 128 + kk] =
                f2bf(bw[(size_t)(blk * 128 + kk) * 128 + n]);
        }
    } else {
        int b = bid - nE - 46;
        int sH = tid >> 7;
        int j = tid & 127;
        const float* w = sH ? g0w1 : g0w0;
        const float* eb = enc + b * 256;
        float acc = 0.f;
        for (int c = 0; c < 256; ++c) acc = fmaf(eb[c], w[(131 + c) * 128 + j], acc);
        encp[(sH * B_ + b) * 128 + j] = acc;
    }
}

// ---------------- single-pass pixel projection via MFMA (full K per block) ----------------
// One block per (level, pixel-tile, batch). Loops all 64-wide K chunks of the
// level, accumulating in registers; writes pp directly (no q partials/reduce).
__global__ __launch_bounds__(256) void proj_all_k(
    const float* __restrict__ fm1, const float* __restrict__ fm2,
    const float* __restrict__ fm3, const float* __restrict__ fm4,
    const unsigned short* __restrict__ bwT, float* __restrict__ o1, float* __restrict__ o2,
    float* __restrict__ o3, float* __restrict__ o4, int B_) {
    __shared__ unsigned short wlds[8192];  // 16 KB: [128 n][64 k] bf16, XOR-swizzled

    int tid = threadIdx.x;
    int n1 = 49 * B_, n2 = 13 * B_, n3 = 4 * B_;
    int bid = blockIdx.x;
    const float* fm;
    float* op;
    int C, HW, PT, idx, koff;
    if (bid < n1) {
        fm = fm1; op = o1; C = 256; HW = 3136; PT = 49; idx = bid; koff = 0;
    } else if (bid < n1 + n2) {
        fm = fm2; op = o2; C = 512; HW = 784; PT = 13; idx = bid - n1; koff = 256;
    } else if (bid < n1 + n2 + n3) {
        fm = fm3; op = o3; C = 1024; HW = 196; PT = 4; idx = bid - n1 - n2; koff = 768;
    } else {
        fm = fm4; op = o4; C = 2048; HW = 49; PT = 1; idx = bid - n1 - n2 - n3; koff = 1792;
    }
    int pt = idx % PT;
    int b = idx / PT;
    int p0 = pt * 64;
    const float* fmb = fm + (size_t)b * C * HW;

    int wave = tid >> 6, lane = tid & 63;
    int row16 = lane & 15, quad = lane >> 4;
    int p = p0 + wave * 16 + row16;
    bool pok = (p < HW);
    int pc = pok ? p : 0;

    floatx4 acc[8];
#pragma unroll
    for (int j = 0; j < 8; ++j) acc[j] = (floatx4){0.f, 0.f, 0.f, 0.f};

    int nz = C >> 6;
    for (int z = 0; z < nz; ++z) {
        int kcf = z * 64;
        int kcw = koff + kcf;
        __syncthreads();  // protect previous iteration's wlds reads
#pragma unroll
        for (int l = 0; l < 4; ++l) {
            int i2 = tid + l * 256;  // 0..1023
            int n = i2 >> 3, c16 = i2 & 7;
            *(short8*)&wlds[n * 64 + ((c16 ^ (n & 7)) * 8)] =
                *(const short8*)(bwT + (size_t)n * 3840 + kcw + c16 * 8);
        }
        short8 ax[2];
#pragma unroll
        for (int ks = 0; ks < 2; ++ks) {
#pragma unroll
            for (int j = 0; j < 8; ++j) {
                float v = pok ? fmb[(size_t)(kcf + ks * 32 + quad * 8 + j) * HW + pc] : 0.f;
                ax[ks][j] = (short)f2bf(v);
            }
        }
        __syncthreads();
#pragma unroll
        for (int ks = 0; ks < 2; ++ks) {
            int c = ks * 4 + quad;
#pragma unroll
            for (int nt = 0; nt < 8; ++nt) {
                int wr = nt * 16 + row16;
                short8 bwf = *(short8*)&wlds[wr * 64 + ((c ^ (wr & 7)) * 8)];
                acc[nt] = __builtin_amdgcn_mfma_f32_16x16x32_bf16(ax[ks], bwf, acc[nt], 0, 0, 0);
            }
        }
    }

    float* obase = op + (size_t)b * HW * 128;
#pragma unroll
    for (int nt = 0; nt < 8; ++nt) {
        int colg = nt * 16 + row16;
#pragma unroll
        for (int rr = 0; rr < 4; ++rr) {
            int pr = p0 + wave * 16 + quad * 4 + rr;
            if (pr < HW) obase[(size_t)pr * 128 + colg] = acc[nt][rr];
        }
    }
}

// ---------------- bilinear sample + bottleneck relu + layer0 pre terms ----------------
__device__ __forceinline__ float sample_level(const float* __restrict__ pp, int Hh, int Ww,
                                              float gx, float gy, int j) {
    float x = (gx + 1.f) * 0.5f * (float)(Ww - 1);
    float y = (gy + 1.f) * 0.5f * (float)(Hh - 1);
    float x0f = floorf(x), y0f = floorf(y);
    float wx1 = x - x0f, wy1 = y - y0f;
    float wx0 = 1.f - wx1, wy0 = 1.f - wy1;
    int x0 = (int)fminf(fmaxf(x0f, 0.f), (float)(Ww - 1));
    int x1 = (int)fminf(fmaxf(x0f + 1.f, 0.f), (float)(Ww - 1));
    int y0 = (int)fminf(fmaxf(y0f, 0.f), (float)(Hh - 1));
    int y1 = (int)fminf(fmaxf(y0f + 1.f, 0.f), (float)(Hh - 1));
    const float* r00 = pp + (size_t)(y0 * Ww + x0) * 128;
    const float* r01 = pp + (size_t)(y0 * Ww + x1) * 128;
    const float* r10 = pp + (size_t)(y1 * Ww + x0) * 128;
    const float* r11 = pp + (size_t)(y1 * Ww + x1) * 128;
    return wy0 * (wx0 * r00[j] + wx1 * r01[j]) + wy1 * (wx0 * r10[j] + wx1 * r11[j]);
}

__global__ __launch_bounds__(128) void sample_bottleneck_k(
    const float* __restrict__ av, const float* __restrict__ pp1, const float* __restrict__ pp2,
    const float* __restrict__ pp3, const float* __restrict__ pp4, const float* __restrict__ bb,
    const float* __restrict__ verts, const float* __restrict__ encp,
    const float* __restrict__ g0w0, const float* __restrict__ g0w1,
    const float* __restrict__ g0b0, const float* __restrict__ g0b1,
    unsigned short* __restrict__ X, unsigned short* __restrict__ H, int V_, int B_) {
    int n = blockIdx.x, j = threadIdx.x;
    int b = n / V_;
    float gx = av[(size_t)n * 3 + 0];
    float gy = av[(size_t)n * 3 + 1];
    float acc = bb[j];
    acc += sample_level(pp1 + (size_t)b * 3136 * 128, 56, 56, gx, gy, j);
    acc += sample_level(pp2 + (size_t)b * 784 * 128, 28, 28, gx, gy, j);
    acc += sample_level(pp3 + (size_t)b * 196 * 128, 14, 14, gx, gy, j);
    acc += sample_level(pp4 + (size_t)b * 49 * 128, 7, 7, gx, gy, j);
    X[(size_t)n * 128 + j] = f2bf(fmaxf(acc, 0.f));
    float v0 = verts[n * 3 + 0], v1 = verts[n * 3 + 1], v2 = verts[n * 3 + 2];
    float h0 = encp[(0 * B_ + b) * 128 + j] + g0b0[j] + v0 * g0w0[128 * 128 + j] +
               v1 * g0w0[129 * 128 + j] + v2 * g0w0[130 * 128 + j];
    float h1 = encp[(1 * B_ + b) * 128 + j] + g0b1[j] + v0 * g0w1[128 * 128 + j] +
               v1 * g0w1[129 * 128 + j] + v2 * g0w1[130 * 128 + j];
    H[(size_t)n * 256 + j] = f2bf(h0);
    H[(size_t)n * 256 + 128 + j] = f2bf(h1);
}

// ---------------- XCD-batch vertex mapping for gather kernels ----------------
__device__ __forceinline__ int xcd_vertex(int bid, int wave, int V_, int B_, int Nv) {
    if (B_ == 4) {
        int xcd = bid & 7;
        int lb = (bid >> 3) * 2 + (xcd & 1);
        int lv = lb * 4 + wave;
        if (lv >= V_) return -1;
        return (xcd >> 1) * V_ + lv;
    }
    int n = bid * 4 + wave;
    return (n < Nv) ? n : -1;
}

// ---------------- layer-0 pre: pre[n] = h0pre[n] + sum_nb h1pre[nb] (fp32) ----------------
__global__ __launch_bounds__(256) void aggpre_k(const unsigned short* __restrict__ H,
                                                const int* __restrict__ rowptr,
                                                const int* __restrict__ adj,
                                                float* __restrict__ pre, int Nv, int V_,
                                                int B_) {
    int wave = threadIdx.x >> 6, lane = threadIdx.x & 63;
    int n = xcd_vertex(blockIdx.x, wave, V_, B_, Nv);
    if (n < 0) return;
    unsigned int u = *(const unsigned int*)(H + (size_t)n * 256 + 2 * lane);
    float a0 = bf2f((unsigned short)(u & 0xffff));
    float a1 = bf2f((unsigned short)(u >> 16));
    int s = rowptr[n], e = rowptr[n + 1];
    for (int t = s; t < e; t += 8) {
        int nb[8];
        unsigned int w[8];
#pragma unroll
        for (int q = 0; q < 8; ++q) {
            int idx = (t + q < e) ? (t + q) : (e - 1);
            nb[q] = adj[idx];
        }
#pragma unroll
        for (int q = 0; q < 8; ++q)
            w[q] = *(const unsigned int*)(H + (size_t)nb[q] * 256 + 128 + 2 * lane);
#pragma unroll
        for (int q = 0; q < 8; ++q) {
            if (t + q < e) {
                a0 += bf2f((unsigned short)(w[q] & 0xffff));
                a1 += bf2f((unsigned short)(w[q] >> 16));
            }
        }
    }
    pre[(size_t)n * 128 + 2 * lane] = a0;
    pre[(size_t)n * 128 + 2 * lane + 1] = a1;
}

// ---------------- fused per-layer: in-block gather (LDS) + dual GEMM ----------------
// Block = 128 rows x 64 cols (y-half). 4 waves. LDS = 32KB weights + 32KB agg
// tile (+bias) = 64.5KB -> 2 blocks/CU (8 waves/CU). Tiles are batch-aligned
// (TB=ceil(V/128) tiles per batch); batch pinned to one XCD pair so the gather
// working set (2.6MB X slice) stays L2-resident, and layer l's X writes land
// in the L2 that layer l+1 reads. Gather uses the flattened-CSR 8-wide walker
// (32 rows/wave -> ~24 pipelined batches). Agg never touches global.
__global__ __launch_bounds__(256, 2) void layer_k(
    const unsigned short* __restrict__ Xin, const int* __restrict__ rowptr,
    const int* __restrict__ adj,
    const unsigned short* __restrict__ Wt,  // [2][128][128] bf16 n-major (W0, W1)
    const float* __restrict__ b0, const float* __restrict__ b1,
    const float* __restrict__ pre, const int* __restrict__ degv,
    unsigned short* __restrict__ Xout, int V_, int B_, int TB) {
    __shared__ unsigned short wlds[16384];  // 32 KB: weight col-half (W0|W1)
    __shared__ unsigned short aggs[16384];  // 32 KB: agg tile [128][128] swz; reused as cs
    __shared__ float bS[128];

    int x = blockIdx.x, yb = blockIdx.y;
    int b, lt;
    if (B_ == 4) {
        int xcd = x & 7;
        b = xcd >> 1;
        lt = (x >> 3) * 2 + (xcd & 1);
    } else {
        b = x / TB;
        lt = x % TB;
    }
    if (lt >= TB) return;
    int m0 = b * V_ + lt * 128;
    int bEnd = (b + 1) * V_;
    int vrows = min(128, V_ - lt * 128);

    int tid = threadIdx.x;
    int wave = tid >> 6, lane = tid & 63;
    int row16 = lane & 15;
    int quad = lane >> 4;

    // CSR bounds for this wave's 32 rows (contiguous adj slice)
    int gbase = m0 + wave * 32;
    int rend_l = rowptr[min(gbase + 1 + lane, bEnd)];  // lanes 0..31 used
    int sWv = rowptr[min(gbase, bEnd)];
    int eWv = __shfl(rend_l, 31);

    // prefetch A(X) frags + deg (overlap with staging/gather)
    short8 axT[2][4];
    int dgT[2][4];
#pragma unroll
    for (int t = 0; t < 2; ++t) {
        int g = min(m0 + t * 64 + wave * 16 + row16, bEnd - 1);
#pragma unroll
        for (int ks = 0; ks < 4; ++ks)
            axT[t][ks] = *(const short8*)(Xin + (size_t)g * 128 + ks * 32 + quad * 8);
#pragma unroll
        for (int rr = 0; rr < 4; ++rr)
            dgT[t][rr] = degv[min(m0 + t * 64 + wave * 16 + quad * 4 + rr, bEnd - 1)];
    }

    if (tid < 64) {
        bS[tid] = b0 ? b0[yb * 64 + tid] : 0.f;
        bS[64 + tid] = b1 ? b1[yb * 64 + tid] : 0.f;
    }

    // weight staging: col-half pair (W0,W1), 2048 16B chunks, XOR-swizzled
    const unsigned short* W0h = Wt + (size_t)yb * 64 * 128;
    const unsigned short* W1h = Wt + 16384 + (size_t)yb * 64 * 128;
#pragma unroll
    for (int l = 0; l < 8; ++l) {
        int idx = tid + l * 256;  // 0..2047
        int half = idx >> 10;
        int r = (idx >> 4) & 63;
        int c16 = idx & 15;
        int sw = (c16 ^ (r & 15)) * 8;
        const unsigned short* src = (half ? W1h : W0h) + r * 128 + c16 * 8;
        *(short8*)&wlds[half * 8192 + r * 128 + sw] = *(const short8*)src;
    }

    // gather: flattened adjacency walk, 8-wide batched, flush rows into aggs
    {
        const unsigned int* Xu = (const unsigned int*)Xin;
        float a0 = 0.f, a1 = 0.f;
        int r = 0;
        int nextEnd = __shfl(rend_l, 0);
        auto flush = [&](int rloc, float v0, float v1) {
            unsigned int o = (unsigned int)f2bf(v0) | ((unsigned int)f2bf(v1) << 16);
            int rl = wave * 32 + rloc;
            *(unsigned int*)&aggs[rl * 128 + (((lane >> 2) ^ (rl & 15)) * 8) +
                                  (lane & 3) * 2] = o;
        };
        for (int t = sWv; t < eWv; t += 8) {
            int nb[8];
            unsigned int w[8];
#pragma unroll
            for (int q = 0; q < 8; ++q) {
                int idx = (t + q < eWv) ? (t + q) : (eWv - 1);
                nb[q] = adj[idx];
            }
#pragma unroll
            for (int q = 0; q < 8; ++q) w[q] = Xu[(size_t)nb[q] * 64 + lane];
#pragma unroll
            for (int q = 0; q < 8; ++q) {
                int pos = t + q;
                if (pos < eWv) {
                    while (pos >= nextEnd) {  // wave-uniform; r stays <= 31 here
                        flush(r, a0, a1);
                        a0 = 0.f;
                        a1 = 0.f;
                        ++r;
                        nextEnd = __shfl(rend_l, r);
                    }
                    a0 += bf2f((unsigned short)(w[q] & 0xffff));
                    a1 += bf2f((unsigned short)(w[q] >> 16));
                }
            }
        }
        while (r < 32) {  // trailing rows (incl. empty / past-batch rows -> zeros)
            flush(r, a0, a1);
            a0 = 0.f;
            a1 = 0.f;
            ++r;
        }
    }
    __syncthreads();

    // MFMA: both 64-row sub-tiles; weight frags reused across sub-tiles
    floatx4 acc[2][4];
#pragma unroll
    for (int t = 0; t < 2; ++t)
#pragma unroll
        for (int j = 0; j < 4; ++j) acc[t][j] = (floatx4){0.f, 0.f, 0.f, 0.f};

#pragma unroll
    for (int ks = 0; ks < 4; ++ks) {
        int c = ks * 4 + quad;
        short8 agf[2];
#pragma unroll
        for (int t = 0; t < 2; ++t) {
            int rlA = t * 64 + wave * 16 + row16;
            agf[t] = *(short8*)&aggs[rlA * 128 + ((c ^ row16) * 8)];
        }
#pragma unroll
        for (int nt = 0; nt < 4; ++nt) {
            int wr = nt * 16 + row16;
            short8 bw0 = *(short8*)&wlds[wr * 128 + ((c ^ row16) * 8)];
            short8 bw1 = *(short8*)&wlds[8192 + wr * 128 + ((c ^ row16) * 8)];
#pragma unroll
            for (int t = 0; t < 2; ++t) {
                acc[t][nt] =
                    __builtin_amdgcn_mfma_f32_16x16x32_bf16(axT[t][ks], bw0, acc[t][nt], 0, 0, 0);
                acc[t][nt] =
                    __builtin_amdgcn_mfma_f32_16x16x32_bf16(agf[t], bw1, acc[t][nt], 0, 0, 0);
            }
        }
    }
    __syncthreads();  // all aggs reads done before epilogue reuses it

    // epilogue -> cs (= reused aggs buffer; 128x72 shorts)
    unsigned short* cs = aggs;
#pragma unroll
    for (int t = 0; t < 2; ++t) {
#pragma unroll
        for (int nt = 0; nt < 4; ++nt) {
            int colh = nt * 16 + row16;
            int colg = yb * 64 + colh;
            float bc0 = bS[colh];
            float bc1 = bS[64 + colh];
#pragma unroll
            for (int rr = 0; rr < 4; ++rr) {
                int row = t * 64 + wave * 16 + quad * 4 + rr;
                float v = acc[t][nt][rr] + bc0 + (float)dgT[t][rr] * bc1;
                if (pre && row < vrows) v += pre[(size_t)(m0 + row) * 128 + colg];
                cs[row * 72 + colh] = f2bf(fmaxf(v, 0.f));
            }
        }
    }
    __syncthreads();

    // coalesced copy-out: 2 threads/row cover 64 cols (128B/row)
    {
        int r = tid >> 1;
        if (r < vrows) {
            int ch = (tid & 1) * 32;
            unsigned short* dst = Xout + (size_t)(m0 + r) * 128 + yb * 64 + ch;
#pragma unroll
            for (int cc = 0; cc < 4; ++cc)
                *(short8*)(dst + cc * 8) = *(short8*)&cs[r * 72 + ch + cc * 8];
        }
    }
}

// ---------------- head: out = X @ off_w + off_b (wave per vertex) ----------------
__global__ __launch_bounds__(256) void head_k(const unsigned short* __restrict__ X,
                                              const float* __restrict__ off_w,
                                              const float* __restrict__ off_b,
                                              float* __restrict__ out, int Nv) {
    int wave = threadIdx.x >> 6, lane = threadIdx.x & 63;
    int n = blockIdx.x * 4 + wave;
    if (n >= Nv) return;
    unsigned int u = *(const unsigned int*)(X + (size_t)n * 128 + 2 * lane);
    float x0 = bf2f((unsigned short)(u & 0xffff));
    float x1 = bf2f((unsigned short)(u >> 16));
    int c0 = 2 * lane, c1 = 2 * lane + 1;
    float p0 = x0 * off_w[c0 * 3 + 0] + x1 * off_w[c1 * 3 + 0];
    float p1 = x0 * off_w[c0 * 3 + 1] + x1 * off_w[c1 * 3 + 1];
    float p2 = x0 * off_w[c0 * 3 + 2] + x1 * off_w[c1 * 3 + 2];
#pragma unroll
    for (int m = 1; m < 64; m <<= 1) {
        p0 += __shfl_xor(p0, m);
        p1 += __shfl_xor(p1, m);
        p2 += __shfl_xor(p2, m);
    }
    if (lane == 0) {
        out[n * 3 + 0] = p0 + off_b[0];
        out[n * 3 + 1] = p1 + off_b[1];
        out[n * 3 + 2] = p2 + off_b[2];
    }
}

extern "C" void kernel_launch(void* const* d_in, const int* in_sizes, int n_in, void* d_out,
                              int out_size, void* d_ws, size_t ws_size, hipStream_t stream) {
    const float* feat1 = (const float*)d_in[0];
    const float* feat2 = (const float*)d_in[1];
    const float* feat3 = (const float*)d_in[2];
    const float* feat4 = (const float*)d_in[3];
    const float* av = (const float*)d_in[4];
    const float* verts = (const float*)d_in[5];
    const float* image_enc = (const float*)d_in[6];
    const int* edges = (const int*)d_in[7];
    const float* bw = (const float*)d_in[8];
    const float* bb = (const float*)d_in[9];
    const float* g0w0 = (const float*)d_in[10];
    const float* g0b0 = (const float*)d_in[11];
    const float* g0w1 = (const float*)d_in[12];
    const float* g0b1 = (const float*)d_in[13];
    const float* gw0 = (const float*)d_in[14];
    const float* gb0 = (const float*)d_in[15];
    const float* gw1 = (const float*)d_in[16];
    const float* gb1 = (const float*)d_in[17];
    const float* off_w = (const float*)d_in[18];
    const float* off_b = (const float*)d_in[19];

    int B_ = in_sizes[6] / 256;  // 4
    int N_ = in_sizes[5] / 3;    // 40968
    int V_ = N_ / B_;            // 10242
    int E_ = in_sizes[7] / 2;    // 122880

    char* wsb = (char*)d_ws;
    size_t off = 0;
    auto alloc = [&](size_t bytes) -> void* {
        void* p = (void*)(wsb + off);
        off += (bytes + 255) & ~(size_t)255;
        return p;
    };
    int S1 = B_ * 3136 * 128;
    int S2 = B_ * 784 * 128;
    int S3 = B_ * 196 * 128;
    int S4 = B_ * 49 * 128;
    float* pp1 = (float*)alloc((size_t)S1 * 4);
    float* pp2 = (float*)alloc((size_t)S2 * 4);
    float* pp3 = (float*)alloc((size_t)S3 * 4);
    float* pp4 = (float*)alloc((size_t)S4 * 4);
    unsigned short* XA = (unsigned short*)alloc((size_t)N_ * 128 * 2);
    unsigned short* XB = (unsigned short*)alloc((size_t)N_ * 128 * 2);
    unsigned short* Hb = (unsigned short*)alloc((size_t)N_ * 256 * 2);
    float* pre = (float*)alloc((size_t)N_ * 128 * 4);
    unsigned short* Wt = (unsigned short*)alloc((size_t)8 * 2 * 128 * 128 * 2);
    unsigned short* bwT = (unsigned short*)alloc((size_t)128 * 3840 * 2);
    float* encp = (float*)alloc((size_t)2 * B_ * 128 * 4);
    int* deg = (int*)alloc((size_t)(N_ + 1) * 4);
    int* rowptr = (int*)alloc((size_t)(N_ + 1) * 4);
    int* cursor = (int*)alloc((size_t)N_ * 4);
    int* excl = (int*)alloc((size_t)N_ * 4);
    int* bsum = (int*)alloc((size_t)64 * 4);
    int* adj = (int*)alloc((size_t)2 * E_ * 4);

    hipMemsetAsync(deg, 0, (N_ + 1) * sizeof(int), stream);

    // fat prologue: count_deg | prep_w | prep_bwT | enc_proj
    int nE = ceil_div(E_, 256);
    fatpre_k<<<nE + 46 + B_, 256, 0, stream>>>(edges, deg, E_, nE, g0w0, g0w1, gw0, gw1, Wt,
                                               bw, bwT, image_enc, encp, B_);

    // CSR scan + fill
    int nb = ceil_div(N_, 1024);
    scan1_k<<<nb, 1024, 0, stream>>>(deg, excl, bsum, N_);
    scan2_k<<<1, 64, 0, stream>>>(bsum, nb);
    scan3_k<<<nb, 1024, 0, stream>>>(excl, bsum, deg, rowptr, cursor, N_);
    fill_adj_k<<<ceil_div(E_, 256), 256, 0, stream>>>(edges, cursor, adj, E_);

    // single-pass pixel projection (full K per block) -> pp directly
    int nproj = (49 + 13 + 4 + 1) * B_;
    proj_all_k<<<nproj, 256, 0, stream>>>(feat1, feat2, feat3, feat4, bwT, pp1, pp2, pp3, pp4,
                                          B_);

    // sample + bottleneck -> XA (bf16 X0); layer0 pre terms (biases baked) -> Hb (bf16)
    sample_bottleneck_k<<<N_, 128, 0, stream>>>(av, pp1, pp2, pp3, pp4, bb, verts, encp, g0w0,
                                                g0w1, g0b0, g0b1, XA, Hb, V_, B_);

    // layer0 pre = h0pre + sum_nb h1pre (XCD-batch swizzled gather)
    int agrid = (B_ == 4) ? 8 * ceil_div(ceil_div(V_, 4), 2) : ceil_div(N_, 4);
    aggpre_k<<<agrid, 256, 0, stream>>>(Hb, rowptr, adj, pre, N_, V_, B_);

    // fused layers: in-block gather + dual GEMM, batch-aligned 128-row tiles
    int TB = ceil_div(V_, 128);
    dim3 lgrid((B_ == 4) ? 8 * ceil_div(TB, 2) : B_ * TB, 2);
    layer_k<<<lgrid, 256, 0, stream>>>(XA, rowptr, adj, Wt, nullptr, nullptr, pre, deg, XB, V_,
                                       B_, TB);
    unsigned short* Xc = XB;
    unsigned short* Xn = XA;
    for (int i = 0; i < 7; ++i) {
        layer_k<<<lgrid, 256, 0, stream>>>(Xc, rowptr, adj, Wt + (size_t)(i + 1) * 32768,
                                           gb0 + i * 128, gb1 + i * 128, nullptr, deg, Xn, V_,
                                           B_, TB);
        unsigned short* t = Xc;
        Xc = Xn;
        Xn = t;
    }
    head_k<<<ceil_div(N_, 4), 256, 0, stream>>>(Xc, off_w, off_b, (float*)d_out, N_);
}

// Round 4
// 522.830 us; speedup vs baseline: 1.4157x; 1.4157x over previous
//
#include <hip/hip_runtime.h>

static inline int ceil_div(int a, int b) { return (a + b - 1) / b; }

typedef __attribute__((ext_vector_type(8))) short short8;
typedef __attribute__((ext_vector_type(4))) float floatx4;

__device__ __forceinline__ unsigned short f2bf(float f) {
    unsigned int u = __float_as_uint(f);
    unsigned int r = (u + 0x7fffu + ((u >> 16) & 1u)) >> 16;
    return (unsigned short)r;
}
__device__ __forceinline__ float bf2f(unsigned short h) {
    return __uint_as_float(((unsigned int)h) << 16);
}

// ---------------- CSR scan ----------------
__global__ __launch_bounds__(1024) void scan1_k(const int* __restrict__ deg,
                                                int* __restrict__ excl,
                                                int* __restrict__ bsum, int Nv) {
    __shared__ int s[1024];
    int tid = threadIdx.x;
    int i = blockIdx.x * 1024 + tid;
    int v = (i < Nv) ? deg[i] : 0;
    s[tid] = v;
    __syncthreads();
    for (int off = 1; off < 1024; off <<= 1) {
        int t = (tid >= off) ? s[tid - off] : 0;
        __syncthreads();
        if (tid >= off) s[tid] += t;
        __syncthreads();
    }
    if (i < Nv) excl[i] = s[tid] - v;
    if (tid == 1023) bsum[blockIdx.x] = s[1023];
}

__global__ __launch_bounds__(64) void scan2_k(int* __restrict__ bsum, int nb) {
    __shared__ int s[64];
    int tid = threadIdx.x;
    int v = (tid < nb) ? bsum[tid] : 0;
    s[tid] = v;
    __syncthreads();
    for (int off = 1; off < 64; off <<= 1) {
        int t = (tid >= off) ? s[tid - off] : 0;
        __syncthreads();
        if (tid >= off) s[tid] += t;
        __syncthreads();
    }
    if (tid < nb) bsum[tid] = s[tid] - v;
}

__global__ __launch_bounds__(1024) void scan3_k(const int* __restrict__ excl,
                                                const int* __restrict__ bsum,
                                                const int* __restrict__ deg,
                                                int* __restrict__ rowptr,
                                                int* __restrict__ cursor, int Nv) {
    int i = blockIdx.x * 1024 + threadIdx.x;
    if (i < Nv) {
        int val = excl[i] + bsum[blockIdx.x];
        rowptr[i] = val;
        cursor[i] = val;
        if (i == Nv - 1) rowptr[Nv] = val + deg[i];
    }
}

__global__ __launch_bounds__(256) void fill_adj_k(const int* __restrict__ edges,
                                                  int* __restrict__ cursor,
                                                  int* __restrict__ adj, int E) {
    int e = blockIdx.x * blockDim.x + threadIdx.x;
    if (e < E) {
        int a = edges[2 * e], b = edges[2 * e + 1];
        adj[atomicAdd(&cursor[a], 1)] = b;
        adj[atomicAdd(&cursor[b], 1)] = a;
    }
}

// ---------------- fat prologue: count_deg | prep_w | prep_bwT | enc_proj ----------------
__global__ __launch_bounds__(256) void fatpre_k(const int* __restrict__ edges,
                                                int* __restrict__ deg, int E, int nE,
                                                const float* __restrict__ g0w0,
                                                const float* __restrict__ g0w1,
                                                const float* __restrict__ gw0,
                                                const float* __restrict__ gw1,
                                                unsigned short* __restrict__ Wt,
                                                const float* __restrict__ bw,
                                                unsigned short* __restrict__ bwT,
                                                const float* __restrict__ enc,
                                                float* __restrict__ encp, int B_) {
    int bid = blockIdx.x;
    int tid = threadIdx.x;
    if (bid < nE) {
        int e = bid * 256 + tid;
        if (e < E) {
            atomicAdd(&deg[edges[2 * e]], 1);
            atomicAdd(&deg[edges[2 * e + 1]], 1);
        }
    } else if (bid < nE + 16) {
        int lh = bid - nE;
        int l = lh >> 1, h = lh & 1;
        const float* src;
        if (l == 0) src = h ? g0w1 : g0w0;
        else src = (h ? gw1 : gw0) + (size_t)(l - 1) * 16384;
        unsigned short* dst = Wt + (size_t)lh * 16384;
        for (int idx = tid; idx < 16384; idx += 256) {
            int n = idx >> 7, k = idx & 127;
            dst[n * 128 + k] = f2bf(src[k * 128 + n]);
        }
    } else if (bid < nE + 46) {
        // bottleneck weight transpose+cast: bwT[n][k] = bf16(bw[k][n])
        int blk = bid - nE - 16;  // 0..29
        for (int idx = tid; idx < 16384; idx += 256) {
            int n = idx >> 7, kk = idx & 127;
            bwT[(size_t)n * 3840 + blk * 128 + kk] =
                f2bf(bw[(size_t)(blk * 128 + kk) * 128 + n]);
        }
    } else {
        int b = bid - nE - 46;
        int sH = tid >> 7;
        int j = tid & 127;
        const float* w = sH ? g0w1 : g0w0;
        const float* eb = enc + b * 256;
        float acc = 0.f;
        for (int c = 0; c < 256; ++c) acc = fmaf(eb[c], w[(131 + c) * 128 + j], acc);
        encp[(sH * B_ + b) * 128 + j] = acc;
    }
}

// ---------------- fused pixel projection via MFMA (z-parallel, two-stage) ----------------
__global__ __launch_bounds__(256) void proj_all_k(
    const float* __restrict__ fm1, const float* __restrict__ fm2,
    const float* __restrict__ fm3, const float* __restrict__ fm4,
    const unsigned short* __restrict__ bwT, float* __restrict__ q1, float* __restrict__ q2,
    float* __restrict__ q3, float* __restrict__ q4, int B_) {
    __shared__ unsigned short wlds[8192];  // 16 KB: [128 n][64 k] bf16, XOR-swizzled

    int tid = threadIdx.x;
    int n1 = 49 * B_ * 4, n2 = 13 * B_ * 8, n3 = 4 * B_ * 16;
    int bid = blockIdx.x;
    const float* fm;
    float* op;
    int C, HW, PT, idx, koff;
    if (bid < n1) {
        fm = fm1; op = q1; C = 256; HW = 3136; PT = 49; idx = bid; koff = 0;
    } else if (bid < n1 + n2) {
        fm = fm2; op = q2; C = 512; HW = 784; PT = 13; idx = bid - n1; koff = 256;
    } else if (bid < n1 + n2 + n3) {
        fm = fm3; op = q3; C = 1024; HW = 196; PT = 4; idx = bid - n1 - n2; koff = 768;
    } else {
        fm = fm4; op = q4; C = 2048; HW = 49; PT = 1; idx = bid - n1 - n2 - n3; koff = 1792;
    }
    int pt = idx % PT;
    int r2 = idx / PT;
    int b = r2 % B_;
    int zz = r2 / B_;
    int p0 = pt * 64;
    int S = B_ * HW * 128;
    const float* fmb = fm + (size_t)b * C * HW;
    int kcf = zz * 64;         // channel offset within this level's feature map
    int kcw = koff + kcf;      // k offset within bwT

    // stage W^T tile [128][64] bf16, swizzled (8 chunks of 16B per row)
#pragma unroll
    for (int l = 0; l < 4; ++l) {
        int i2 = tid + l * 256;  // 0..1023
        int n = i2 >> 3, c16 = i2 & 7;
        *(short8*)&wlds[n * 64 + ((c16 ^ (n & 7)) * 8)] =
            *(const short8*)(bwT + (size_t)n * 3840 + kcw + c16 * 8);
    }

    int wave = tid >> 6, lane = tid & 63;
    int row16 = lane & 15, quad = lane >> 4;
    int p = p0 + wave * 16 + row16;
    bool pok = (p < HW);
    int pc = pok ? p : 0;
    short8 ax[2];
#pragma unroll
    for (int ks = 0; ks < 2; ++ks) {
#pragma unroll
        for (int j = 0; j < 8; ++j) {
            float v = pok ? fmb[(size_t)(kcf + ks * 32 + quad * 8 + j) * HW + pc] : 0.f;
            ax[ks][j] = (short)f2bf(v);
        }
    }
    __syncthreads();

    floatx4 acc[8];
#pragma unroll
    for (int j = 0; j < 8; ++j) acc[j] = (floatx4){0.f, 0.f, 0.f, 0.f};
#pragma unroll
    for (int ks = 0; ks < 2; ++ks) {
        int c = ks * 4 + quad;
#pragma unroll
        for (int nt = 0; nt < 8; ++nt) {
            int wr = nt * 16 + row16;
            short8 bwf = *(short8*)&wlds[wr * 64 + ((c ^ (wr & 7)) * 8)];
            acc[nt] = __builtin_amdgcn_mfma_f32_16x16x32_bf16(ax[ks], bwf, acc[nt], 0, 0, 0);
        }
    }

    float* obase = op + (size_t)zz * S + (size_t)b * HW * 128;
#pragma unroll
    for (int nt = 0; nt < 8; ++nt) {
        int colg = nt * 16 + row16;
#pragma unroll
        for (int rr = 0; rr < 4; ++rr) {
            int pr = p0 + wave * 16 + quad * 4 + rr;
            if (pr < HW) obase[(size_t)pr * 128 + colg] = acc[nt][rr];
        }
    }
}

// ---------------- reduce partials for all 4 levels ----------------
__global__ __launch_bounds__(256) void reduce4_k(const float* __restrict__ q1,
                                                 const float* __restrict__ q2,
                                                 const float* __restrict__ q3,
                                                 const float* __restrict__ q4,
                                                 float* __restrict__ o1, float* __restrict__ o2,
                                                 float* __restrict__ o3, float* __restrict__ o4,
                                                 int S1, int S2, int S3, int S4) {
    int i = (blockIdx.x * 256 + threadIdx.x) * 4;
    const float* src;
    float* dst;
    int S, z, base;
    if (i < S1) {
        src = q1; dst = o1; S = S1; z = 4; base = i;
    } else if (i < S1 + S2) {
        src = q2; dst = o2; S = S2; z = 8; base = i - S1;
    } else if (i < S1 + S2 + S3) {
        src = q3; dst = o3; S = S3; z = 16; base = i - S1 - S2;
    } else if (i < S1 + S2 + S3 + S4) {
        src = q4; dst = o4; S = S4; z = 32; base = i - S1 - S2 - S3;
    } else {
        return;
    }
    float4 a = *(const float4*)(src + base);
    for (int zz = 1; zz < z; ++zz) {
        float4 b = *(const float4*)(src + (size_t)zz * S + base);
        a.x += b.x; a.y += b.y; a.z += b.z; a.w += b.w;
    }
    *(float4*)(dst + base) = a;
}

// ---------------- bilinear sample + bottleneck relu + layer0 pre terms ----------------
__device__ __forceinline__ float sample_level(const float* __restrict__ pp, int Hh, int Ww,
                                              float gx, float gy, int j) {
    float x = (gx + 1.f) * 0.5f * (float)(Ww - 1);
    float y = (gy + 1.f) * 0.5f * (float)(Hh - 1);
    float x0f = floorf(x), y0f = floorf(y);
    float wx1 = x - x0f, wy1 = y - y0f;
    float wx0 = 1.f - wx1, wy0 = 1.f - wy1;
    int x0 = (int)fminf(fmaxf(x0f, 0.f), (float)(Ww - 1));
    int x1 = (int)fminf(fmaxf(x0f + 1.f, 0.f), (float)(Ww - 1));
    int y0 = (int)fminf(fmaxf(y0f, 0.f), (float)(Hh - 1));
    int y1 = (int)fminf(fmaxf(y0f + 1.f, 0.f), (float)(Hh - 1));
    const float* r00 = pp + (size_t)(y0 * Ww + x0) * 128;
    const float* r01 = pp + (size_t)(y0 * Ww + x1) * 128;
    const float* r10 = pp + (size_t)(y1 * Ww + x0) * 128;
    const float* r11 = pp + (size_t)(y1 * Ww + x1) * 128;
    return wy0 * (wx0 * r00[j] + wx1 * r01[j]) + wy1 * (wx0 * r10[j] + wx1 * r11[j]);
}

__global__ __launch_bounds__(128) void sample_bottleneck_k(
    const float* __restrict__ av, const float* __restrict__ pp1, const float* __restrict__ pp2,
    const float* __restrict__ pp3, const float* __restrict__ pp4, const float* __restrict__ bb,
    const float* __restrict__ verts, const float* __restrict__ encp,
    const float* __restrict__ g0w0, const float* __restrict__ g0w1,
    const float* __restrict__ g0b0, const float* __restrict__ g0b1,
    unsigned short* __restrict__ X, unsigned short* __restrict__ H, int V_, int B_) {
    int n = blockIdx.x, j = threadIdx.x;
    int b = n / V_;
    float gx = av[(size_t)n * 3 + 0];
    float gy = av[(size_t)n * 3 + 1];
    float acc = bb[j];
    acc += sample_level(pp1 + (size_t)b * 3136 * 128, 56, 56, gx, gy, j);
    acc += sample_level(pp2 + (size_t)b * 784 * 128, 28, 28, gx, gy, j);
    acc += sample_level(pp3 + (size_t)b * 196 * 128, 14, 14, gx, gy, j);
    acc += sample_level(pp4 + (size_t)b * 49 * 128, 7, 7, gx, gy, j);
    X[(size_t)n * 128 + j] = f2bf(fmaxf(acc, 0.f));
    float v0 = verts[n * 3 + 0], v1 = verts[n * 3 + 1], v2 = verts[n * 3 + 2];
    float h0 = encp[(0 * B_ + b) * 128 + j] + g0b0[j] + v0 * g0w0[128 * 128 + j] +
               v1 * g0w0[129 * 128 + j] + v2 * g0w0[130 * 128 + j];
    float h1 = encp[(1 * B_ + b) * 128 + j] + g0b1[j] + v0 * g0w1[128 * 128 + j] +
               v1 * g0w1[129 * 128 + j] + v2 * g0w1[130 * 128 + j];
    H[(size_t)n * 256 + j] = f2bf(h0);
    H[(size_t)n * 256 + 128 + j] = f2bf(h1);
}

// ---------------- persistent XCD-pinned gather bodies ----------------
// Grid of exactly 1024 blocks (4/CU, fully co-resident) so the round-robin
// blockIdx->XCD assignment holds for the whole kernel. XCD pair {2b,2b+1}
// handles batch b only: its 2.6 MB X-slice stays L2-resident across the
// ~6 touches/vertex. Each wave grid-strides ~10 vertices.

__device__ __forceinline__ void aggpre_vertex(const unsigned short* __restrict__ H,
                                              const int* __restrict__ rowptr,
                                              const int* __restrict__ adj,
                                              float* __restrict__ pre, int n, int lane) {
    unsigned int u = *(const unsigned int*)(H + (size_t)n * 256 + 2 * lane);
    float a0 = bf2f((unsigned short)(u & 0xffff));
    float a1 = bf2f((unsigned short)(u >> 16));
    int s = rowptr[n], e = rowptr[n + 1];
    for (int t = s; t < e; t += 8) {
        int nb[8];
        unsigned int w[8];
#pragma unroll
        for (int q = 0; q < 8; ++q) {
            int idx = (t + q < e) ? (t + q) : (e - 1);
            nb[q] = adj[idx];
        }
#pragma unroll
        for (int q = 0; q < 8; ++q)
            w[q] = *(const unsigned int*)(H + (size_t)nb[q] * 256 + 128 + 2 * lane);
#pragma unroll
        for (int q = 0; q < 8; ++q) {
            if (t + q < e) {
                a0 += bf2f((unsigned short)(w[q] & 0xffff));
                a1 += bf2f((unsigned short)(w[q] >> 16));
            }
        }
    }
    pre[(size_t)n * 128 + 2 * lane] = a0;
    pre[(size_t)n * 128 + 2 * lane + 1] = a1;
}

__global__ __launch_bounds__(256) void aggpre_k(const unsigned short* __restrict__ H,
                                                const int* __restrict__ rowptr,
                                                const int* __restrict__ adj,
                                                float* __restrict__ pre, int Nv, int V_,
                                                int B_) {
    int wave = threadIdx.x >> 6, lane = threadIdx.x & 63;
    if (B_ == 4) {
        int bid = blockIdx.x;
        int xcd = bid & 7;
        int b = xcd >> 1;
        int c = ((bid >> 3) * 2 + (xcd & 1)) * 4 + wave;  // chain id in [0,1024)
        for (int lv = c; lv < V_; lv += 1024)
            aggpre_vertex(H, rowptr, adj, pre, b * V_ + lv, lane);
    } else {
        int n = blockIdx.x * 4 + wave;
        if (n < Nv) aggpre_vertex(H, rowptr, adj, pre, n, lane);
    }
}

__device__ __forceinline__ void agg_vertex(const unsigned int* __restrict__ Xu,
                                           const int* __restrict__ rowptr,
                                           const int* __restrict__ adj,
                                           unsigned short* __restrict__ Agg, int n, int lane) {
    float a0 = 0.f, a1 = 0.f;
    int s = rowptr[n], e = rowptr[n + 1];
    for (int t = s; t < e; t += 8) {
        int nb[8];
        unsigned int w[8];
#pragma unroll
        for (int q = 0; q < 8; ++q) {
            int idx = (t + q < e) ? (t + q) : (e - 1);
            nb[q] = adj[idx];
        }
#pragma unroll
        for (int q = 0; q < 8; ++q) w[q] = Xu[(size_t)nb[q] * 64 + lane];
#pragma unroll
        for (int q = 0; q < 8; ++q) {
            if (t + q < e) {
                a0 += bf2f((unsigned short)(w[q] & 0xffff));
                a1 += bf2f((unsigned short)(w[q] >> 16));
            }
        }
    }
    unsigned int o = (unsigned int)f2bf(a0) | ((unsigned int)f2bf(a1) << 16);
    *(unsigned int*)(Agg + (size_t)n * 128 + 2 * lane) = o;
}

__global__ __launch_bounds__(256) void agg_x_k(const unsigned short* __restrict__ X,
                                               const int* __restrict__ rowptr,
                                               const int* __restrict__ adj,
                                               unsigned short* __restrict__ Agg, int Nv,
                                               int V_, int B_) {
    int wave = threadIdx.x >> 6, lane = threadIdx.x & 63;
    const unsigned int* Xu = (const unsigned int*)X;
    if (B_ == 4) {
        int bid = blockIdx.x;
        int xcd = bid & 7;
        int b = xcd >> 1;
        int c = ((bid >> 3) * 2 + (xcd & 1)) * 4 + wave;  // chain id in [0,1024)
        for (int lv = c; lv < V_; lv += 1024)
            agg_vertex(Xu, rowptr, adj, Agg, b * V_ + lv, lane);
    } else {
        int n = blockIdx.x * 4 + wave;
        if (n < Nv) agg_vertex(Xu, rowptr, adj, Agg, n, lane);
    }
}

// ---------------- dual-MFMA layer GEMM v3: 128-row x 64-col tiles ----------------
__global__ __launch_bounds__(256, 3) void gemm_dual_k(
    const unsigned short* __restrict__ Xin, const unsigned short* __restrict__ Agg,
    const unsigned short* __restrict__ Wt,  // [2][128][128] bf16 n-major (W0, W1)
    const float* __restrict__ b0, const float* __restrict__ b1,
    const float* __restrict__ pre, const int* __restrict__ degv,
    unsigned short* __restrict__ Xout, int M) {
    __shared__ unsigned short wlds[16384];  // 32 KB weights (stays live both sub-tiles)
    __shared__ unsigned short cs[64 * 72];  // 9 KB epilogue staging
    __shared__ float bS[128];

    int tid = threadIdx.x;
    int m0 = blockIdx.x * 128;
    int yb = blockIdx.y;

    int wave = tid >> 6, lane = tid & 63;
    int row16 = lane & 15;
    int quad = lane >> 4;
    int wrow = wave * 16;

    // prefetch A + deg for sub-tile 0 (overlaps weight staging)
    short8 axT[2][4], agT[2][4];
    int dgT[2][4];
    {
        int g = min(m0 + wrow + row16, M - 1);
#pragma unroll
        for (int ks = 0; ks < 4; ++ks) {
            int koff = ks * 32 + quad * 8;
            axT[0][ks] = *(const short8*)(Xin + (size_t)g * 128 + koff);
            agT[0][ks] = *(const short8*)(Agg + (size_t)g * 128 + koff);
        }
#pragma unroll
        for (int rr = 0; rr < 4; ++rr)
            dgT[0][rr] = degv[min(m0 + wrow + quad * 4 + rr, M - 1)];
    }

    if (tid < 64) {
        bS[tid] = b0 ? b0[yb * 64 + tid] : 0.f;
        bS[64 + tid] = b1 ? b1[yb * 64 + tid] : 0.f;
    }

    const unsigned short* W0h = Wt + (size_t)yb * 64 * 128;
    const unsigned short* W1h = Wt + 16384 + (size_t)yb * 64 * 128;
#pragma unroll
    for (int l = 0; l < 8; ++l) {
        int idx = tid + l * 256;      // 0..2047 16B chunks
        int half = idx >> 10;
        int r = (idx >> 4) & 63;
        int c16 = idx & 15;
        int sw = (c16 ^ (r & 15)) * 8;
        const unsigned short* src = (half ? W1h : W0h) + r * 128 + c16 * 8;
        *(short8*)&wlds[half * 8192 + r * 128 + sw] = *(const short8*)src;
    }
    __syncthreads();

    // prefetch A + deg for sub-tile 1 (overlaps sub-tile-0 MFMA)
    {
        int g = min(m0 + 64 + wrow + row16, M - 1);
#pragma unroll
        for (int ks = 0; ks < 4; ++ks) {
            int koff = ks * 32 + quad * 8;
            axT[1][ks] = *(const short8*)(Xin + (size_t)g * 128 + koff);
            agT[1][ks] = *(const short8*)(Agg + (size_t)g * 128 + koff);
        }
#pragma unroll
        for (int rr = 0; rr < 4; ++rr)
            dgT[1][rr] = degv[min(m0 + 64 + wrow + quad * 4 + rr, M - 1)];
    }

#pragma unroll
    for (int t = 0; t < 2; ++t) {
        int mT = m0 + t * 64;
        floatx4 acc[4];
#pragma unroll
        for (int j = 0; j < 4; j++) acc[j] = (floatx4){0.f, 0.f, 0.f, 0.f};

#pragma unroll
        for (int ks = 0; ks < 4; ++ks) {
            int c = ks * 4 + quad;
#pragma unroll
            for (int nt = 0; nt < 4; ++nt) {
                int wr = nt * 16 + row16;
                short8 bw0 = *(short8*)&wlds[wr * 128 + ((c ^ row16) * 8)];
                short8 bw1 = *(short8*)&wlds[8192 + wr * 128 + ((c ^ row16) * 8)];
                acc[nt] = __builtin_amdgcn_mfma_f32_16x16x32_bf16(axT[t][ks], bw0, acc[nt], 0, 0, 0);
                acc[nt] = __builtin_amdgcn_mfma_f32_16x16x32_bf16(agT[t][ks], bw1, acc[nt], 0, 0, 0);
            }
        }

        // epilogue -> cs (each wave writes its own 16 rows)
#pragma unroll
        for (int nt = 0; nt < 4; ++nt) {
            int colh = nt * 16 + row16;
            int colg = yb * 64 + colh;
            float bc0 = bS[colh];
            float bc1 = bS[64 + colh];
#pragma unroll
            for (int rr = 0; rr < 4; ++rr) {
                int row = wrow + quad * 4 + rr;
                int gm = mT + row;
                float v = acc[nt][rr] + bc0 + (float)dgT[t][rr] * bc1;
                if (pre && gm < M) v += pre[(size_t)gm * 128 + colg];
                cs[row * 72 + colh] = f2bf(fmaxf(v, 0.f));
            }
        }
        __syncthreads();

        // coalesced copy-out
        {
            int r = tid >> 2;
            int cq = (tid & 3) * 16;
            int gm = mT + r;
            if (gm < M) {
                unsigned short* dst = Xout + (size_t)gm * 128 + yb * 64 + cq;
                *(short8*)dst = *(short8*)&cs[r * 72 + cq];
                *(short8*)(dst + 8) = *(short8*)&cs[r * 72 + cq + 8];
            }
        }
        __syncthreads();  // cs reads done before next sub-tile overwrites
    }
}

// ---------------- head: out = X @ off_w + off_b (wave per vertex) ----------------
__global__ __launch_bounds__(256) void head_k(const unsigned short* __restrict__ X,
                                              const float* __restrict__ off_w,
                                              const float* __restrict__ off_b,
                                              float* __restrict__ out, int Nv) {
    int wave = threadIdx.x >> 6, lane = threadIdx.x & 63;
    int n = blockIdx.x * 4 + wave;
    if (n >= Nv) return;
    unsigned int u = *(const unsigned int*)(X + (size_t)n * 128 + 2 * lane);
    float x0 = bf2f((unsigned short)(u & 0xffff));
    float x1 = bf2f((unsigned short)(u >> 16));
    int c0 = 2 * lane, c1 = 2 * lane + 1;
    float p0 = x0 * off_w[c0 * 3 + 0] + x1 * off_w[c1 * 3 + 0];
    float p1 = x0 * off_w[c0 * 3 + 1] + x1 * off_w[c1 * 3 + 1];
    float p2 = x0 * off_w[c0 * 3 + 2] + x1 * off_w[c1 * 3 + 2];
#pragma unroll
    for (int m = 1; m < 64; m <<= 1) {
        p0 += __shfl_xor(p0, m);
        p1 += __shfl_xor(p1, m);
        p2 += __shfl_xor(p2, m);
    }
    if (lane == 0) {
        out[n * 3 + 0] = p0 + off_b[0];
        out[n * 3 + 1] = p1 + off_b[1];
        out[n * 3 + 2] = p2 + off_b[2];
    }
}

extern "C" void kernel_launch(void* const* d_in, const int* in_sizes, int n_in, void* d_out,
                              int out_size, void* d_ws, size_t ws_size, hipStream_t stream) {
    const float* feat1 = (const float*)d_in[0];
    const float* feat2 = (const float*)d_in[1];
    const float* feat3 = (const float*)d_in[2];
    const float* feat4 = (const float*)d_in[3];
    const float* av = (const float*)d_in[4];
    const float* verts = (const float*)d_in[5];
    const float* image_enc = (const float*)d_in[6];
    const int* edges = (const int*)d_in[7];
    const float* bw = (const float*)d_in[8];
    const float* bb = (const float*)d_in[9];
    const float* g0w0 = (const float*)d_in[10];
    const float* g0b0 = (const float*)d_in[11];
    const float* g0w1 = (const float*)d_in[12];
    const float* g0b1 = (const float*)d_in[13];
    const float* gw0 = (const float*)d_in[14];
    const float* gb0 = (const float*)d_in[15];
    const float* gw1 = (const float*)d_in[16];
    const float* gb1 = (const float*)d_in[17];
    const float* off_w = (const float*)d_in[18];
    const float* off_b = (const float*)d_in[19];

    int B_ = in_sizes[6] / 256;  // 4
    int N_ = in_sizes[5] / 3;    // 40968
    int V_ = N_ / B_;            // 10242
    int E_ = in_sizes[7] / 2;    // 122880

    char* wsb = (char*)d_ws;
    size_t off = 0;
    auto alloc = [&](size_t bytes) -> void* {
        void* p = (void*)(wsb + off);
        off += (bytes + 255) & ~(size_t)255;
        return p;
    };
    int S1 = B_ * 3136 * 128;
    int S2 = B_ * 784 * 128;
    int S3 = B_ * 196 * 128;
    int S4 = B_ * 49 * 128;
    float* pp1 = (float*)alloc((size_t)S1 * 4);
    float* pp2 = (float*)alloc((size_t)S2 * 4);
    float* pp3 = (float*)alloc((size_t)S3 * 4);
    float* pp4 = (float*)alloc((size_t)S4 * 4);
    float* q1 = (float*)alloc((size_t)4 * S1 * 4);
    float* q2 = (float*)alloc((size_t)8 * S2 * 4);
    float* q3 = (float*)alloc((size_t)16 * S3 * 4);
    float* q4 = (float*)alloc((size_t)32 * S4 * 4);
    unsigned short* XA = (unsigned short*)alloc((size_t)N_ * 128 * 2);
    unsigned short* XB = (unsigned short*)alloc((size_t)N_ * 128 * 2);
    unsigned short* AggB = (unsigned short*)alloc((size_t)N_ * 128 * 2);
    unsigned short* Hb = (unsigned short*)alloc((size_t)N_ * 256 * 2);
    float* pre = (float*)alloc((size_t)N_ * 128 * 4);
    unsigned short* Wt = (unsigned short*)alloc((size_t)8 * 2 * 128 * 128 * 2);
    unsigned short* bwT = (unsigned short*)alloc((size_t)128 * 3840 * 2);
    float* encp = (float*)alloc((size_t)2 * B_ * 128 * 4);
    int* deg = (int*)alloc((size_t)(N_ + 1) * 4);
    int* rowptr = (int*)alloc((size_t)(N_ + 1) * 4);
    int* cursor = (int*)alloc((size_t)N_ * 4);
    int* excl = (int*)alloc((size_t)N_ * 4);
    int* bsum = (int*)alloc((size_t)64 * 4);
    int* adj = (int*)alloc((size_t)2 * E_ * 4);

    hipMemsetAsync(deg, 0, (N_ + 1) * sizeof(int), stream);

    // fat prologue: count_deg | prep_w | prep_bwT | enc_proj
    int nE = ceil_div(E_, 256);
    fatpre_k<<<nE + 46 + B_, 256, 0, stream>>>(edges, deg, E_, nE, g0w0, g0w1, gw0, gw1, Wt,
                                               bw, bwT, image_enc, encp, B_);

    // CSR scan + fill
    int nb = ceil_div(N_, 1024);
    scan1_k<<<nb, 1024, 0, stream>>>(deg, excl, bsum, N_);
    scan2_k<<<1, 64, 0, stream>>>(bsum, nb);
    scan3_k<<<nb, 1024, 0, stream>>>(excl, bsum, deg, rowptr, cursor, N_);
    fill_adj_k<<<ceil_div(E_, 256), 256, 0, stream>>>(edges, cursor, adj, E_);

    // fused pixel projection via MFMA (z-parallel) + 4-level reduce
    int nproj = 49 * B_ * 4 + 13 * B_ * 8 + 4 * B_ * 16 + 1 * B_ * 32;
    proj_all_k<<<nproj, 256, 0, stream>>>(feat1, feat2, feat3, feat4, bwT, q1, q2, q3, q4, B_);
    int tot4 = (S1 + S2 + S3 + S4) / 4;
    reduce4_k<<<ceil_div(tot4, 256), 256, 0, stream>>>(q1, q2, q3, q4, pp1, pp2, pp3, pp4, S1,
                                                       S2, S3, S4);

    // sample + bottleneck -> XA (bf16 X0); layer0 pre terms (biases baked) -> Hb (bf16)
    sample_bottleneck_k<<<N_, 128, 0, stream>>>(av, pp1, pp2, pp3, pp4, bb, verts, encp, g0w0,
                                                g0w1, g0b0, g0b1, XA, Hb, V_, B_);

    // persistent XCD-pinned gather grid (fully co-resident) when B_==4
    int agrid = (B_ == 4) ? 1024 : ceil_div(N_, 4);

    // layer0 pre = h0pre + sum_nb h1pre
    aggpre_k<<<agrid, 256, 0, stream>>>(Hb, rowptr, adj, pre, N_, V_, B_);

    dim3 ggrid(ceil_div(N_, 128), 2);
    // layer 0: pre supplies all affine terms
    agg_x_k<<<agrid, 256, 0, stream>>>(XA, rowptr, adj, AggB, N_, V_, B_);
    gemm_dual_k<<<ggrid, 256, 0, stream>>>(XA, AggB, Wt, nullptr, nullptr, pre, deg, XB, N_);
    unsigned short* Xc = XB;
    unsigned short* Xn = XA;
    for (int i = 0; i < 7; ++i) {
        agg_x_k<<<agrid, 256, 0, stream>>>(Xc, rowptr, adj, AggB, N_, V_, B_);
        gemm_dual_k<<<ggrid, 256, 0, stream>>>(Xc, AggB, Wt + (size_t)(i + 1) * 32768,
                                               gb0 + i * 128, gb1 + i * 128, nullptr, deg, Xn,
                                               N_);
        unsigned short* t = Xc;
        Xc = Xn;
        Xn = t;
    }
    head_k<<<ceil_div(N_, 4), 256, 0, stream>>>(Xc, off_w, off_b, (float*)d_out, N_);
}

// Round 5
// 472.642 us; speedup vs baseline: 1.5660x; 1.1062x over previous
//
#include <hip/hip_runtime.h>

static inline int ceil_div(int a, int b) { return (a + b - 1) / b; }

typedef __attribute__((ext_vector_type(8))) short short8;
typedef __attribute__((ext_vector_type(4))) float floatx4;

__device__ __forceinline__ unsigned short f2bf(float f) {
    unsigned int u = __float_as_uint(f);
    unsigned int r = (u + 0x7fffu + ((u >> 16) & 1u)) >> 16;
    return (unsigned short)r;
}
__device__ __forceinline__ float bf2f(unsigned short h) {
    return __uint_as_float(((unsigned int)h) << 16);
}

// ---------------- CSR scan ----------------
__global__ __launch_bounds__(1024) void scan1_k(const int* __restrict__ deg,
                                                int* __restrict__ excl,
                                                int* __restrict__ bsum, int Nv) {
    __shared__ int s[1024];
    int tid = threadIdx.x;
    int i = blockIdx.x * 1024 + tid;
    int v = (i < Nv) ? deg[i] : 0;
    s[tid] = v;
    __syncthreads();
    for (int off = 1; off < 1024; off <<= 1) {
        int t = (tid >= off) ? s[tid - off] : 0;
        __syncthreads();
        if (tid >= off) s[tid] += t;
        __syncthreads();
    }
    if (i < Nv) excl[i] = s[tid] - v;
    if (tid == 1023) bsum[blockIdx.x] = s[1023];
}

__global__ __launch_bounds__(64) void scan2_k(int* __restrict__ bsum, int nb) {
    __shared__ int s[64];
    int tid = threadIdx.x;
    int v = (tid < nb) ? bsum[tid] : 0;
    s[tid] = v;
    __syncthreads();
    for (int off = 1; off < 64; off <<= 1) {
        int t = (tid >= off) ? s[tid - off] : 0;
        __syncthreads();
        if (tid >= off) s[tid] += t;
        __syncthreads();
    }
    if (tid < nb) bsum[tid] = s[tid] - v;
}

__global__ __launch_bounds__(1024) void scan3_k(const int* __restrict__ excl,
                                                const int* __restrict__ bsum,
                                                const int* __restrict__ deg,
                                                int* __restrict__ rowptr,
                                                int* __restrict__ cursor, int Nv) {
    int i = blockIdx.x * 1024 + threadIdx.x;
    if (i < Nv) {
        int val = excl[i] + bsum[blockIdx.x];
        rowptr[i] = val;
        cursor[i] = val;
        if (i == Nv - 1) rowptr[Nv] = val + deg[i];
    }
}

__global__ __launch_bounds__(256) void fill_adj_k(const int* __restrict__ edges,
                                                  int* __restrict__ cursor,
                                                  int* __restrict__ adj, int E) {
    int e = blockIdx.x * blockDim.x + threadIdx.x;
    if (e < E) {
        int a = edges[2 * e], b = edges[2 * e + 1];
        adj[atomicAdd(&cursor[a], 1)] = b;
        adj[atomicAdd(&cursor[b], 1)] = a;
    }
}

// ---------------- fat prologue: count_deg | prep_w | prep_bwT | enc_proj ----------------
__global__ __launch_bounds__(256) void fatpre_k(const int* __restrict__ edges,
                                                int* __restrict__ deg, int E, int nE,
                                                const float* __restrict__ g0w0,
                                                const float* __restrict__ g0w1,
                                                const float* __restrict__ gw0,
                                                const float* __restrict__ gw1,
                                                unsigned short* __restrict__ Wt,
                                                const float* __restrict__ bw,
                                                unsigned short* __restrict__ bwT,
                                                const float* __restrict__ enc,
                                                float* __restrict__ encp, int B_) {
    int bid = blockIdx.x;
    int tid = threadIdx.x;
    if (bid < nE) {
        int e = bid * 256 + tid;
        if (e < E) {
            atomicAdd(&deg[edges[2 * e]], 1);
            atomicAdd(&deg[edges[2 * e + 1]], 1);
        }
    } else if (bid < nE + 16) {
        int lh = bid - nE;
        int l = lh >> 1, h = lh & 1;
        const float* src;
        if (l == 0) src = h ? g0w1 : g0w0;
        else src = (h ? gw1 : gw0) + (size_t)(l - 1) * 16384;
        unsigned short* dst = Wt + (size_t)lh * 16384;
        for (int idx = tid; idx < 16384; idx += 256) {
            int n = idx >> 7, k = idx & 127;
            dst[n * 128 + k] = f2bf(src[k * 128 + n]);
        }
    } else if (bid < nE + 46) {
        // bottleneck weight transpose+cast: bwT[n][k] = bf16(bw[k][n])
        int blk = bid - nE - 16;  // 0..29
        for (int idx = tid; idx < 16384; idx += 256) {
            int n = idx >> 7, kk = idx & 127;
            bwT[(size_t)n * 3840 + blk * 128 + kk] =
                f2bf(bw[(size_t)(blk * 128 + kk) * 128 + n]);
        }
    } else {
        int b = bid - nE - 46;
        int sH = tid >> 7;
        int j = tid & 127;
        const float* w = sH ? g0w1 : g0w0;
        const float* eb = enc + b * 256;
        float acc = 0.f;
        for (int c = 0; c < 256; ++c) acc = fmaf(eb[c], w[(131 + c) * 128 + j], acc);
        encp[(sH * B_ + b) * 128 + j] = acc;
    }
}

// ---------------- fused pixel projection via MFMA (z-parallel, two-stage) ----------------
__global__ __launch_bounds__(256) void proj_all_k(
    const float* __restrict__ fm1, const float* __restrict__ fm2,
    const float* __restrict__ fm3, const float* __restrict__ fm4,
    const unsigned short* __restrict__ bwT, float* __restrict__ q1, float* __restrict__ q2,
    float* __restrict__ q3, float* __restrict__ q4, int B_) {
    __shared__ unsigned short wlds[8192];  // 16 KB: [128 n][64 k] bf16, XOR-swizzled

    int tid = threadIdx.x;
    int n1 = 49 * B_ * 4, n2 = 13 * B_ * 8, n3 = 4 * B_ * 16;
    int bid = blockIdx.x;
    const float* fm;
    float* op;
    int C, HW, PT, idx, koff;
    if (bid < n1) {
        fm = fm1; op = q1; C = 256; HW = 3136; PT = 49; idx = bid; koff = 0;
    } else if (bid < n1 + n2) {
        fm = fm2; op = q2; C = 512; HW = 784; PT = 13; idx = bid - n1; koff = 256;
    } else if (bid < n1 + n2 + n3) {
        fm = fm3; op = q3; C = 1024; HW = 196; PT = 4; idx = bid - n1 - n2; koff = 768;
    } else {
        fm = fm4; op = q4; C = 2048; HW = 49; PT = 1; idx = bid - n1 - n2 - n3; koff = 1792;
    }
    int pt = idx % PT;
    int r2 = idx / PT;
    int b = r2 % B_;
    int zz = r2 / B_;
    int p0 = pt * 64;
    int S = B_ * HW * 128;
    const float* fmb = fm + (size_t)b * C * HW;
    int kcf = zz * 64;         // channel offset within this level's feature map
    int kcw = koff + kcf;      // k offset within bwT

    // stage W^T tile [128][64] bf16, swizzled (8 chunks of 16B per row)
#pragma unroll
    for (int l = 0; l < 4; ++l) {
        int i2 = tid + l * 256;  // 0..1023
        int n = i2 >> 3, c16 = i2 & 7;
        *(short8*)&wlds[n * 64 + ((c16 ^ (n & 7)) * 8)] =
            *(const short8*)(bwT + (size_t)n * 3840 + kcw + c16 * 8);
    }

    int wave = tid >> 6, lane = tid & 63;
    int row16 = lane & 15, quad = lane >> 4;
    int p = p0 + wave * 16 + row16;
    bool pok = (p < HW);
    int pc = pok ? p : 0;
    short8 ax[2];
#pragma unroll
    for (int ks = 0; ks < 2; ++ks) {
#pragma unroll
        for (int j = 0; j < 8; ++j) {
            float v = pok ? fmb[(size_t)(kcf + ks * 32 + quad * 8 + j) * HW + pc] : 0.f;
            ax[ks][j] = (short)f2bf(v);
        }
    }
    __syncthreads();

    floatx4 acc[8];
#pragma unroll
    for (int j = 0; j < 8; ++j) acc[j] = (floatx4){0.f, 0.f, 0.f, 0.f};
#pragma unroll
    for (int ks = 0; ks < 2; ++ks) {
        int c = ks * 4 + quad;
#pragma unroll
        for (int nt = 0; nt < 8; ++nt) {
            int wr = nt * 16 + row16;
            short8 bwf = *(short8*)&wlds[wr * 64 + ((c ^ (wr & 7)) * 8)];
            acc[nt] = __builtin_amdgcn_mfma_f32_16x16x32_bf16(ax[ks], bwf, acc[nt], 0, 0, 0);
        }
    }

    float* obase = op + (size_t)zz * S + (size_t)b * HW * 128;
#pragma unroll
    for (int nt = 0; nt < 8; ++nt) {
        int colg = nt * 16 + row16;
#pragma unroll
        for (int rr = 0; rr < 4; ++rr) {
            int pr = p0 + wave * 16 + quad * 4 + rr;
            if (pr < HW) obase[(size_t)pr * 128 + colg] = acc[nt][rr];
        }
    }
}

// ---------------- reduce partials for all 4 levels ----------------
__global__ __launch_bounds__(256) void reduce4_k(const float* __restrict__ q1,
                                                 const float* __restrict__ q2,
                                                 const float* __restrict__ q3,
                                                 const float* __restrict__ q4,
                                                 float* __restrict__ o1, float* __restrict__ o2,
                                                 float* __restrict__ o3, float* __restrict__ o4,
                                                 int S1, int S2, int S3, int S4) {
    int i = (blockIdx.x * 256 + threadIdx.x) * 4;
    const float* src;
    float* dst;
    int S, z, base;
    if (i < S1) {
        src = q1; dst = o1; S = S1; z = 4; base = i;
    } else if (i < S1 + S2) {
        src = q2; dst = o2; S = S2; z = 8; base = i - S1;
    } else if (i < S1 + S2 + S3) {
        src = q3; dst = o3; S = S3; z = 16; base = i - S1 - S2;
    } else if (i < S1 + S2 + S3 + S4) {
        src = q4; dst = o4; S = S4; z = 32; base = i - S1 - S2 - S3;
    } else {
        return;
    }
    float4 a = *(const float4*)(src + base);
    for (int zz = 1; zz < z; ++zz) {
        float4 b = *(const float4*)(src + (size_t)zz * S + base);
        a.x += b.x; a.y += b.y; a.z += b.z; a.w += b.w;
    }
    *(float4*)(dst + base) = a;
}

// ---------------- bilinear sample + bottleneck relu + layer0 pre terms ----------------
__device__ __forceinline__ float sample_level(const float* __restrict__ pp, int Hh, int Ww,
                                              float gx, float gy, int j) {
    float x = (gx + 1.f) * 0.5f * (float)(Ww - 1);
    float y = (gy + 1.f) * 0.5f * (float)(Hh - 1);
    float x0f = floorf(x), y0f = floorf(y);
    float wx1 = x - x0f, wy1 = y - y0f;
    float wx0 = 1.f - wx1, wy0 = 1.f - wy1;
    int x0 = (int)fminf(fmaxf(x0f, 0.f), (float)(Ww - 1));
    int x1 = (int)fminf(fmaxf(x0f + 1.f, 0.f), (float)(Ww - 1));
    int y0 = (int)fminf(fmaxf(y0f, 0.f), (float)(Hh - 1));
    int y1 = (int)fminf(fmaxf(y0f + 1.f, 0.f), (float)(Hh - 1));
    const float* r00 = pp + (size_t)(y0 * Ww + x0) * 128;
    const float* r01 = pp + (size_t)(y0 * Ww + x1) * 128;
    const float* r10 = pp + (size_t)(y1 * Ww + x0) * 128;
    const float* r11 = pp + (size_t)(y1 * Ww + x1) * 128;
    return wy0 * (wx0 * r00[j] + wx1 * r01[j]) + wy1 * (wx0 * r10[j] + wx1 * r11[j]);
}

__global__ __launch_bounds__(128) void sample_bottleneck_k(
    const float* __restrict__ av, const float* __restrict__ pp1, const float* __restrict__ pp2,
    const float* __restrict__ pp3, const float* __restrict__ pp4, const float* __restrict__ bb,
    const float* __restrict__ verts, const float* __restrict__ encp,
    const float* __restrict__ g0w0, const float* __restrict__ g0w1,
    const float* __restrict__ g0b0, const float* __restrict__ g0b1,
    unsigned short* __restrict__ X, unsigned short* __restrict__ H, int V_, int B_) {
    int n = blockIdx.x, j = threadIdx.x;
    int b = n / V_;
    float gx = av[(size_t)n * 3 + 0];
    float gy = av[(size_t)n * 3 + 1];
    float acc = bb[j];
    acc += sample_level(pp1 + (size_t)b * 3136 * 128, 56, 56, gx, gy, j);
    acc += sample_level(pp2 + (size_t)b * 784 * 128, 28, 28, gx, gy, j);
    acc += sample_level(pp3 + (size_t)b * 196 * 128, 14, 14, gx, gy, j);
    acc += sample_level(pp4 + (size_t)b * 49 * 128, 7, 7, gx, gy, j);
    X[(size_t)n * 128 + j] = f2bf(fmaxf(acc, 0.f));
    float v0 = verts[n * 3 + 0], v1 = verts[n * 3 + 1], v2 = verts[n * 3 + 2];
    float h0 = encp[(0 * B_ + b) * 128 + j] + g0b0[j] + v0 * g0w0[128 * 128 + j] +
               v1 * g0w0[129 * 128 + j] + v2 * g0w0[130 * 128 + j];
    float h1 = encp[(1 * B_ + b) * 128 + j] + g0b1[j] + v0 * g0w1[128 * 128 + j] +
               v1 * g0w1[129 * 128 + j] + v2 * g0w1[130 * 128 + j];
    H[(size_t)n * 256 + j] = f2bf(h0);
    H[(size_t)n * 256 + 128 + j] = f2bf(h1);
}

// ---------------- 2-vertex-interleaved gather (latency/ILP fix) ----------------
// Each wave serves vertices n0 and n0+1: one shared rowptr triple (removes a
// dependent load level) and BOTH vertices' adj + X-row loads issued together
// -> 16 row-loads in flight per wave (vs 8), half the blocks.

__global__ __launch_bounds__(256) void aggpre_k(const unsigned short* __restrict__ H,
                                                const int* __restrict__ rowptr,
                                                const int* __restrict__ adj,
                                                float* __restrict__ pre, int Nv) {
    int wave = threadIdx.x >> 6, lane = threadIdx.x & 63;
    int n0 = (blockIdx.x * 4 + wave) * 2;
    if (n0 >= Nv) return;
    int r0 = rowptr[n0], r1 = rowptr[n0 + 1], r2 = rowptr[n0 + 2];
    unsigned int u0 = *(const unsigned int*)(H + (size_t)n0 * 256 + 2 * lane);
    unsigned int u1 = *(const unsigned int*)(H + (size_t)(n0 + 1) * 256 + 2 * lane);
    float a0 = bf2f((unsigned short)(u0 & 0xffff));
    float a1 = bf2f((unsigned short)(u0 >> 16));
    float b0 = bf2f((unsigned short)(u1 & 0xffff));
    float b1 = bf2f((unsigned short)(u1 >> 16));
    int tA = r0, tB = r1;
    while (tA < r1 || tB < r2) {
        int nbA[8], nbB[8];
        unsigned int wA[8], wB[8];
#pragma unroll
        for (int q = 0; q < 8; ++q) {
            int ia = tA + q; ia = (ia < r1) ? ia : (r1 - 1); ia = (ia < 0) ? 0 : ia;
            nbA[q] = adj[ia];
            int ib = tB + q; ib = (ib < r2) ? ib : (r2 - 1); ib = (ib < 0) ? 0 : ib;
            nbB[q] = adj[ib];
        }
#pragma unroll
        for (int q = 0; q < 8; ++q) {
            wA[q] = *(const unsigned int*)(H + (size_t)nbA[q] * 256 + 128 + 2 * lane);
            wB[q] = *(const unsigned int*)(H + (size_t)nbB[q] * 256 + 128 + 2 * lane);
        }
#pragma unroll
        for (int q = 0; q < 8; ++q) {
            if (tA + q < r1) {
                a0 += bf2f((unsigned short)(wA[q] & 0xffff));
                a1 += bf2f((unsigned short)(wA[q] >> 16));
            }
            if (tB + q < r2) {
                b0 += bf2f((unsigned short)(wB[q] & 0xffff));
                b1 += bf2f((unsigned short)(wB[q] >> 16));
            }
        }
        tA += 8;
        tB += 8;
    }
    pre[(size_t)n0 * 128 + 2 * lane] = a0;
    pre[(size_t)n0 * 128 + 2 * lane + 1] = a1;
    pre[(size_t)(n0 + 1) * 128 + 2 * lane] = b0;
    pre[(size_t)(n0 + 1) * 128 + 2 * lane + 1] = b1;
}

__global__ __launch_bounds__(256) void agg_x_k(const unsigned short* __restrict__ X,
                                               const int* __restrict__ rowptr,
                                               const int* __restrict__ adj,
                                               unsigned short* __restrict__ Agg, int Nv) {
    int wave = threadIdx.x >> 6, lane = threadIdx.x & 63;
    int n0 = (blockIdx.x * 4 + wave) * 2;
    if (n0 >= Nv) return;
    const unsigned int* Xu = (const unsigned int*)X;
    int r0 = rowptr[n0], r1 = rowptr[n0 + 1], r2 = rowptr[n0 + 2];
    float a0 = 0.f, a1 = 0.f, b0 = 0.f, b1 = 0.f;
    int tA = r0, tB = r1;
    while (tA < r1 || tB < r2) {
        int nbA[8], nbB[8];
        unsigned int wA[8], wB[8];
#pragma unroll
        for (int q = 0; q < 8; ++q) {
            int ia = tA + q; ia = (ia < r1) ? ia : (r1 - 1); ia = (ia < 0) ? 0 : ia;
            nbA[q] = adj[ia];
            int ib = tB + q; ib = (ib < r2) ? ib : (r2 - 1); ib = (ib < 0) ? 0 : ib;
            nbB[q] = adj[ib];
        }
#pragma unroll
        for (int q = 0; q < 8; ++q) {
            wA[q] = Xu[(size_t)nbA[q] * 64 + lane];
            wB[q] = Xu[(size_t)nbB[q] * 64 + lane];
        }
#pragma unroll
        for (int q = 0; q < 8; ++q) {
            if (tA + q < r1) {
                a0 += bf2f((unsigned short)(wA[q] & 0xffff));
                a1 += bf2f((unsigned short)(wA[q] >> 16));
            }
            if (tB + q < r2) {
                b0 += bf2f((unsigned short)(wB[q] & 0xffff));
                b1 += bf2f((unsigned short)(wB[q] >> 16));
            }
        }
        tA += 8;
        tB += 8;
    }
    unsigned int oA = (unsigned int)f2bf(a0) | ((unsigned int)f2bf(a1) << 16);
    unsigned int oB = (unsigned int)f2bf(b0) | ((unsigned int)f2bf(b1) << 16);
    *(unsigned int*)(Agg + (size_t)n0 * 128 + 2 * lane) = oA;
    *(unsigned int*)(Agg + (size_t)(n0 + 1) * 128 + 2 * lane) = oB;
}

// ---------------- dual-MFMA layer GEMM v3: 128-row x 64-col tiles ----------------
__global__ __launch_bounds__(256, 3) void gemm_dual_k(
    const unsigned short* __restrict__ Xin, const unsigned short* __restrict__ Agg,
    const unsigned short* __restrict__ Wt,  // [2][128][128] bf16 n-major (W0, W1)
    const float* __restrict__ b0, const float* __restrict__ b1,
    const float* __restrict__ pre, const int* __restrict__ degv,
    unsigned short* __restrict__ Xout, int M) {
    __shared__ unsigned short wlds[16384];  // 32 KB weights (stays live both sub-tiles)
    __shared__ unsigned short cs[64 * 72];  // 9 KB epilogue staging
    __shared__ float bS[128];

    int tid = threadIdx.x;
    int m0 = blockIdx.x * 128;
    int yb = blockIdx.y;

    int wave = tid >> 6, lane = tid & 63;
    int row16 = lane & 15;
    int quad = lane >> 4;
    int wrow = wave * 16;

    // prefetch A + deg for sub-tile 0 (overlaps weight staging)
    short8 axT[2][4], agT[2][4];
    int dgT[2][4];
    {
        int g = min(m0 + wrow + row16, M - 1);
#pragma unroll
        for (int ks = 0; ks < 4; ++ks) {
            int koff = ks * 32 + quad * 8;
            axT[0][ks] = *(const short8*)(Xin + (size_t)g * 128 + koff);
            agT[0][ks] = *(const short8*)(Agg + (size_t)g * 128 + koff);
        }
#pragma unroll
        for (int rr = 0; rr < 4; ++rr)
            dgT[0][rr] = degv[min(m0 + wrow + quad * 4 + rr, M - 1)];
    }

    if (tid < 64) {
        bS[tid] = b0 ? b0[yb * 64 + tid] : 0.f;
        bS[64 + tid] = b1 ? b1[yb * 64 + tid] : 0.f;
    }

    const unsigned short* W0h = Wt + (size_t)yb * 64 * 128;
    const unsigned short* W1h = Wt + 16384 + (size_t)yb * 64 * 128;
#pragma unroll
    for (int l = 0; l < 8; ++l) {
        int idx = tid + l * 256;      // 0..2047 16B chunks
        int half = idx >> 10;
        int r = (idx >> 4) & 63;
        int c16 = idx & 15;
        int sw = (c16 ^ (r & 15)) * 8;
        const unsigned short* src = (half ? W1h : W0h) + r * 128 + c16 * 8;
        *(short8*)&wlds[half * 8192 + r * 128 + sw] = *(const short8*)src;
    }
    __syncthreads();

    // prefetch A + deg for sub-tile 1 (overlaps sub-tile-0 MFMA)
    {
        int g = min(m0 + 64 + wrow + row16, M - 1);
#pragma unroll
        for (int ks = 0; ks < 4; ++ks) {
            int koff = ks * 32 + quad * 8;
            axT[1][ks] = *(const short8*)(Xin + (size_t)g * 128 + koff);
            agT[1][ks] = *(const short8*)(Agg + (size_t)g * 128 + koff);
        }
#pragma unroll
        for (int rr = 0; rr < 4; ++rr)
            dgT[1][rr] = degv[min(m0 + 64 + wrow + quad * 4 + rr, M - 1)];
    }

#pragma unroll
    for (int t = 0; t < 2; ++t) {
        int mT = m0 + t * 64;
        floatx4 acc[4];
#pragma unroll
        for (int j = 0; j < 4; j++) acc[j] = (floatx4){0.f, 0.f, 0.f, 0.f};

#pragma unroll
        for (int ks = 0; ks < 4; ++ks) {
            int c = ks * 4 + quad;
#pragma unroll
            for (int nt = 0; nt < 4; ++nt) {
                int wr = nt * 16 + row16;
                short8 bw0 = *(short8*)&wlds[wr * 128 + ((c ^ row16) * 8)];
                short8 bw1 = *(short8*)&wlds[8192 + wr * 128 + ((c ^ row16) * 8)];
                acc[nt] = __builtin_amdgcn_mfma_f32_16x16x32_bf16(axT[t][ks], bw0, acc[nt], 0, 0, 0);
                acc[nt] = __builtin_amdgcn_mfma_f32_16x16x32_bf16(agT[t][ks], bw1, acc[nt], 0, 0, 0);
            }
        }

        // epilogue -> cs (each wave writes its own 16 rows)
#pragma unroll
        for (int nt = 0; nt < 4; ++nt) {
            int colh = nt * 16 + row16;
            int colg = yb * 64 + colh;
            float bc0 = bS[colh];
            float bc1 = bS[64 + colh];
#pragma unroll
            for (int rr = 0; rr < 4; ++rr) {
                int row = wrow + quad * 4 + rr;
                int gm = mT + row;
                float v = acc[nt][rr] + bc0 + (float)dgT[t][rr] * bc1;
                if (pre && gm < M) v += pre[(size_t)gm * 128 + colg];
                cs[row * 72 + colh] = f2bf(fmaxf(v, 0.f));
            }
        }
        __syncthreads();

        // coalesced copy-out
        {
            int r = tid >> 2;
            int cq = (tid & 3) * 16;
            int gm = mT + r;
            if (gm < M) {
                unsigned short* dst = Xout + (size_t)gm * 128 + yb * 64 + cq;
                *(short8*)dst = *(short8*)&cs[r * 72 + cq];
                *(short8*)(dst + 8) = *(short8*)&cs[r * 72 + cq + 8];
            }
        }
        __syncthreads();  // cs reads done before next sub-tile overwrites
    }
}

// ---------------- head: out = X @ off_w + off_b (wave per vertex) ----------------
__global__ __launch_bounds__(256) void head_k(const unsigned short* __restrict__ X,
                                              const float* __restrict__ off_w,
                                              const float* __restrict__ off_b,
                                              float* __restrict__ out, int Nv) {
    int wave = threadIdx.x >> 6, lane = threadIdx.x & 63;
    int n = blockIdx.x * 4 + wave;
    if (n >= Nv) return;
    unsigned int u = *(const unsigned int*)(X + (size_t)n * 128 + 2 * lane);
    float x0 = bf2f((unsigned short)(u & 0xffff));
    float x1 = bf2f((unsigned short)(u >> 16));
    int c0 = 2 * lane, c1 = 2 * lane + 1;
    float p0 = x0 * off_w[c0 * 3 + 0] + x1 * off_w[c1 * 3 + 0];
    float p1 = x0 * off_w[c0 * 3 + 1] + x1 * off_w[c1 * 3 + 1];
    float p2 = x0 * off_w[c0 * 3 + 2] + x1 * off_w[c1 * 3 + 2];
#pragma unroll
    for (int m = 1; m < 64; m <<= 1) {
        p0 += __shfl_xor(p0, m);
        p1 += __shfl_xor(p1, m);
        p2 += __shfl_xor(p2, m);
    }
    if (lane == 0) {
        out[n * 3 + 0] = p0 + off_b[0];
        out[n * 3 + 1] = p1 + off_b[1];
        out[n * 3 + 2] = p2 + off_b[2];
    }
}

extern "C" void kernel_launch(void* const* d_in, const int* in_sizes, int n_in, void* d_out,
                              int out_size, void* d_ws, size_t ws_size, hipStream_t stream) {
    const float* feat1 = (const float*)d_in[0];
    const float* feat2 = (const float*)d_in[1];
    const float* feat3 = (const float*)d_in[2];
    const float* feat4 = (const float*)d_in[3];
    const float* av = (const float*)d_in[4];
    const float* verts = (const float*)d_in[5];
    const float* image_enc = (const float*)d_in[6];
    const int* edges = (const int*)d_in[7];
    const float* bw = (const float*)d_in[8];
    const float* bb = (const float*)d_in[9];
    const float* g0w0 = (const float*)d_in[10];
    const float* g0b0 = (const float*)d_in[11];
    const float* g0w1 = (const float*)d_in[12];
    const float* g0b1 = (const float*)d_in[13];
    const float* gw0 = (const float*)d_in[14];
    const float* gb0 = (const float*)d_in[15];
    const float* gw1 = (const float*)d_in[16];
    const float* gb1 = (const float*)d_in[17];
    const float* off_w = (const float*)d_in[18];
    const float* off_b = (const float*)d_in[19];

    int B_ = in_sizes[6] / 256;  // 4
    int N_ = in_sizes[5] / 3;    // 40968
    int V_ = N_ / B_;            // 10242
    int E_ = in_sizes[7] / 2;    // 122880

    char* wsb = (char*)d_ws;
    size_t off = 0;
    auto alloc = [&](size_t bytes) -> void* {
        void* p = (void*)(wsb + off);
        off += (bytes + 255) & ~(size_t)255;
        return p;
    };
    int S1 = B_ * 3136 * 128;
    int S2 = B_ * 784 * 128;
    int S3 = B_ * 196 * 128;
    int S4 = B_ * 49 * 128;
    float* pp1 = (float*)alloc((size_t)S1 * 4);
    float* pp2 = (float*)alloc((size_t)S2 * 4);
    float* pp3 = (float*)alloc((size_t)S3 * 4);
    float* pp4 = (float*)alloc((size_t)S4 * 4);
    float* q1 = (float*)alloc((size_t)4 * S1 * 4);
    float* q2 = (float*)alloc((size_t)8 * S2 * 4);
    float* q3 = (float*)alloc((size_t)16 * S3 * 4);
    float* q4 = (float*)alloc((size_t)32 * S4 * 4);
    unsigned short* XA = (unsigned short*)alloc((size_t)N_ * 128 * 2);
    unsigned short* XB = (unsigned short*)alloc((size_t)N_ * 128 * 2);
    unsigned short* AggB = (unsigned short*)alloc((size_t)N_ * 128 * 2);
    unsigned short* Hb = (unsigned short*)alloc((size_t)N_ * 256 * 2);
    float* pre = (float*)alloc((size_t)N_ * 128 * 4);
    unsigned short* Wt = (unsigned short*)alloc((size_t)8 * 2 * 128 * 128 * 2);
    unsigned short* bwT = (unsigned short*)alloc((size_t)128 * 3840 * 2);
    float* encp = (float*)alloc((size_t)2 * B_ * 128 * 4);
    int* deg = (int*)alloc((size_t)(N_ + 1) * 4);
    int* rowptr = (int*)alloc((size_t)(N_ + 1) * 4);
    int* cursor = (int*)alloc((size_t)N_ * 4);
    int* excl = (int*)alloc((size_t)N_ * 4);
    int* bsum = (int*)alloc((size_t)64 * 4);
    int* adj = (int*)alloc((size_t)2 * E_ * 4);

    hipMemsetAsync(deg, 0, (N_ + 1) * sizeof(int), stream);

    // fat prologue: count_deg | prep_w | prep_bwT | enc_proj
    int nE = ceil_div(E_, 256);
    fatpre_k<<<nE + 46 + B_, 256, 0, stream>>>(edges, deg, E_, nE, g0w0, g0w1, gw0, gw1, Wt,
                                               bw, bwT, image_enc, encp, B_);

    // CSR scan + fill
    int nb = ceil_div(N_, 1024);
    scan1_k<<<nb, 1024, 0, stream>>>(deg, excl, bsum, N_);
    scan2_k<<<1, 64, 0, stream>>>(bsum, nb);
    scan3_k<<<nb, 1024, 0, stream>>>(excl, bsum, deg, rowptr, cursor, N_);
    fill_adj_k<<<ceil_div(E_, 256), 256, 0, stream>>>(edges, cursor, adj, E_);

    // fused pixel projection via MFMA (z-parallel) + 4-level reduce
    int nproj = 49 * B_ * 4 + 13 * B_ * 8 + 4 * B_ * 16 + 1 * B_ * 32;
    proj_all_k<<<nproj, 256, 0, stream>>>(feat1, feat2, feat3, feat4, bwT, q1, q2, q3, q4, B_);
    int tot4 = (S1 + S2 + S3 + S4) / 4;
    reduce4_k<<<ceil_div(tot4, 256), 256, 0, stream>>>(q1, q2, q3, q4, pp1, pp2, pp3, pp4, S1,
                                                       S2, S3, S4);

    // sample + bottleneck -> XA (bf16 X0); layer0 pre terms (biases baked) -> Hb (bf16)
    sample_bottleneck_k<<<N_, 128, 0, stream>>>(av, pp1, pp2, pp3, pp4, bb, verts, encp, g0w0,
                                                g0w1, g0b0, g0b1, XA, Hb, V_, B_);

    // 2-vertex-per-wave gather grid
    int agrid = ceil_div(N_, 8);

    // layer0 pre = h0pre + sum_nb h1pre
    aggpre_k<<<agrid, 256, 0, stream>>>(Hb, rowptr, adj, pre, N_);

    dim3 ggrid(ceil_div(N_, 128), 2);
    // layer 0: pre supplies all affine terms
    agg_x_k<<<agrid, 256, 0, stream>>>(XA, rowptr, adj, AggB, N_);
    gemm_dual_k<<<ggrid, 256, 0, stream>>>(XA, AggB, Wt, nullptr, nullptr, pre, deg, XB, N_);
    unsigned short* Xc = XB;
    unsigned short* Xn = XA;
    for (int i = 0; i < 7; ++i) {
        agg_x_k<<<agrid, 256, 0, stream>>>(Xc, rowptr, adj, AggB, N_);
        gemm_dual_k<<<ggrid, 256, 0, stream>>>(Xc, AggB, Wt + (size_t)(i + 1) * 32768,
                                               gb0 + i * 128, gb1 + i * 128, nullptr, deg, Xn,
                                               N_);
        unsigned short* t = Xc;
        Xc = Xn;
        Xn = t;
    }
    head_k<<<ceil_div(N_, 4), 256, 0, stream>>>(Xc, off_w, off_b, (float*)d_out, N_);
}

// Round 6
// 471.514 us; speedup vs baseline: 1.5698x; 1.0024x over previous
//
#include <hip/hip_runtime.h>

static inline int ceil_div(int a, int b) { return (a + b - 1) / b; }

typedef __attribute__((ext_vector_type(8))) short short8;
typedef __attribute__((ext_vector_type(4))) float floatx4;

__device__ __forceinline__ unsigned short f2bf(float f) {
    unsigned int u = __float_as_uint(f);
    unsigned int r = (u + 0x7fffu + ((u >> 16) & 1u)) >> 16;
    return (unsigned short)r;
}
__device__ __forceinline__ float bf2f(unsigned short h) {
    return __uint_as_float(((unsigned int)h) << 16);
}

// ---------------- CSR scan ----------------
__global__ __launch_bounds__(1024) void scan1_k(const int* __restrict__ deg,
                                                int* __restrict__ excl,
                                                int* __restrict__ bsum, int Nv) {
    __shared__ int s[1024];
    int tid = threadIdx.x;
    int i = blockIdx.x * 1024 + tid;
    int v = (i < Nv) ? deg[i] : 0;
    s[tid] = v;
    __syncthreads();
    for (int off = 1; off < 1024; off <<= 1) {
        int t = (tid >= off) ? s[tid - off] : 0;
        __syncthreads();
        if (tid >= off) s[tid] += t;
        __syncthreads();
    }
    if (i < Nv) excl[i] = s[tid] - v;
    if (tid == 1023) bsum[blockIdx.x] = s[1023];
}

__global__ __launch_bounds__(64) void scan2_k(int* __restrict__ bsum, int nb) {
    __shared__ int s[64];
    int tid = threadIdx.x;
    int v = (tid < nb) ? bsum[tid] : 0;
    s[tid] = v;
    __syncthreads();
    for (int off = 1; off < 64; off <<= 1) {
        int t = (tid >= off) ? s[tid - off] : 0;
        __syncthreads();
        if (tid >= off) s[tid] += t;
        __syncthreads();
    }
    if (tid < nb) bsum[tid] = s[tid] - v;
}

__global__ __launch_bounds__(1024) void scan3_k(const int* __restrict__ excl,
                                                const int* __restrict__ bsum,
                                                const int* __restrict__ deg,
                                                int* __restrict__ rowptr,
                                                int* __restrict__ cursor, int Nv) {
    int i = blockIdx.x * 1024 + threadIdx.x;
    if (i < Nv) {
        int val = excl[i] + bsum[blockIdx.x];
        rowptr[i] = val;
        cursor[i] = val;
        if (i == Nv - 1) rowptr[Nv] = val + deg[i];
    }
}

__global__ __launch_bounds__(256) void fill_adj_k(const int* __restrict__ edges,
                                                  int* __restrict__ cursor,
                                                  int* __restrict__ adj, int E) {
    int e = blockIdx.x * blockDim.x + threadIdx.x;
    if (e < E) {
        int a = edges[2 * e], b = edges[2 * e + 1];
        adj[atomicAdd(&cursor[a], 1)] = b;
        adj[atomicAdd(&cursor[b], 1)] = a;
    }
}

// ---------------- fat prologue: count_deg | prep_w | prep_bwT | enc_proj ----------------
__global__ __launch_bounds__(256) void fatpre_k(const int* __restrict__ edges,
                                                int* __restrict__ deg, int E, int nE,
                                                const float* __restrict__ g0w0,
                                                const float* __restrict__ g0w1,
                                                const float* __restrict__ gw0,
                                                const float* __restrict__ gw1,
                                                unsigned short* __restrict__ Wt,
                                                const float* __restrict__ bw,
                                                unsigned short* __restrict__ bwT,
                                                const float* __restrict__ enc,
                                                float* __restrict__ encp, int B_) {
    int bid = blockIdx.x;
    int tid = threadIdx.x;
    if (bid < nE) {
        int e = bid * 256 + tid;
        if (e < E) {
            atomicAdd(&deg[edges[2 * e]], 1);
            atomicAdd(&deg[edges[2 * e + 1]], 1);
        }
    } else if (bid < nE + 16) {
        int lh = bid - nE;
        int l = lh >> 1, h = lh & 1;
        const float* src;
        if (l == 0) src = h ? g0w1 : g0w0;
        else src = (h ? gw1 : gw0) + (size_t)(l - 1) * 16384;
        unsigned short* dst = Wt + (size_t)lh * 16384;
        for (int idx = tid; idx < 16384; idx += 256) {
            int n = idx >> 7, k = idx & 127;
            dst[n * 128 + k] = f2bf(src[k * 128 + n]);
        }
    } else if (bid < nE + 46) {
        // bottleneck weight transpose+cast: bwT[n][k] = bf16(bw[k][n])
        int blk = bid - nE - 16;  // 0..29
        for (int idx = tid; idx < 16384; idx += 256) {
            int n = idx >> 7, kk = idx & 127;
            bwT[(size_t)n * 3840 + blk * 128 + kk] =
                f2bf(bw[(size_t)(blk * 128 + kk) * 128 + n]);
        }
    } else {
        int b = bid - nE - 46;
        int sH = tid >> 7;
        int j = tid & 127;
        const float* w = sH ? g0w1 : g0w0;
        const float* eb = enc + b * 256;
        float acc = 0.f;
        for (int c = 0; c < 256; ++c) acc = fmaf(eb[c], w[(131 + c) * 128 + j], acc);
        encp[(sH * B_ + b) * 128 + j] = acc;
    }
}

// ---------------- pixel projection via MFMA (z-parallel, atomic accumulate) ----------------
// z-blocks atomicAdd their fp32 64x128 tiles directly into pp (zero-initialized)
// -> no q partial buffers, no reduce pass.
__global__ __launch_bounds__(256) void proj_all_k(
    const float* __restrict__ fm1, const float* __restrict__ fm2,
    const float* __restrict__ fm3, const float* __restrict__ fm4,
    const unsigned short* __restrict__ bwT, float* __restrict__ o1, float* __restrict__ o2,
    float* __restrict__ o3, float* __restrict__ o4, int B_) {
    __shared__ unsigned short wlds[8192];  // 16 KB: [128 n][64 k] bf16, XOR-swizzled

    int tid = threadIdx.x;
    int n1 = 49 * B_ * 4, n2 = 13 * B_ * 8, n3 = 4 * B_ * 16;
    int bid = blockIdx.x;
    const float* fm;
    float* op;
    int C, HW, PT, idx, koff;
    if (bid < n1) {
        fm = fm1; op = o1; C = 256; HW = 3136; PT = 49; idx = bid; koff = 0;
    } else if (bid < n1 + n2) {
        fm = fm2; op = o2; C = 512; HW = 784; PT = 13; idx = bid - n1; koff = 256;
    } else if (bid < n1 + n2 + n3) {
        fm = fm3; op = o3; C = 1024; HW = 196; PT = 4; idx = bid - n1 - n2; koff = 768;
    } else {
        fm = fm4; op = o4; C = 2048; HW = 49; PT = 1; idx = bid - n1 - n2 - n3; koff = 1792;
    }
    int pt = idx % PT;
    int r2 = idx / PT;
    int b = r2 % B_;
    int zz = r2 / B_;
    int p0 = pt * 64;
    const float* fmb = fm + (size_t)b * C * HW;
    int kcf = zz * 64;         // channel offset within this level's feature map
    int kcw = koff + kcf;      // k offset within bwT

    // stage W^T tile [128][64] bf16, swizzled (8 chunks of 16B per row)
#pragma unroll
    for (int l = 0; l < 4; ++l) {
        int i2 = tid + l * 256;  // 0..1023
        int n = i2 >> 3, c16 = i2 & 7;
        *(short8*)&wlds[n * 64 + ((c16 ^ (n & 7)) * 8)] =
            *(const short8*)(bwT + (size_t)n * 3840 + kcw + c16 * 8);
    }

    int wave = tid >> 6, lane = tid & 63;
    int row16 = lane & 15, quad = lane >> 4;
    int p = p0 + wave * 16 + row16;
    bool pok = (p < HW);
    int pc = pok ? p : 0;
    short8 ax[2];
#pragma unroll
    for (int ks = 0; ks < 2; ++ks) {
#pragma unroll
        for (int j = 0; j < 8; ++j) {
            float v = pok ? fmb[(size_t)(kcf + ks * 32 + quad * 8 + j) * HW + pc] : 0.f;
            ax[ks][j] = (short)f2bf(v);
        }
    }
    __syncthreads();

    floatx4 acc[8];
#pragma unroll
    for (int j = 0; j < 8; ++j) acc[j] = (floatx4){0.f, 0.f, 0.f, 0.f};
#pragma unroll
    for (int ks = 0; ks < 2; ++ks) {
        int c = ks * 4 + quad;
#pragma unroll
        for (int nt = 0; nt < 8; ++nt) {
            int wr = nt * 16 + row16;
            short8 bwf = *(short8*)&wlds[wr * 64 + ((c ^ (wr & 7)) * 8)];
            acc[nt] = __builtin_amdgcn_mfma_f32_16x16x32_bf16(ax[ks], bwf, acc[nt], 0, 0, 0);
        }
    }

    float* obase = op + (size_t)b * HW * 128;
#pragma unroll
    for (int nt = 0; nt < 8; ++nt) {
        int colg = nt * 16 + row16;
#pragma unroll
        for (int rr = 0; rr < 4; ++rr) {
            int pr = p0 + wave * 16 + quad * 4 + rr;
            if (pr < HW) atomicAdd(&obase[(size_t)pr * 128 + colg], acc[nt][rr]);
        }
    }
}

// ---------------- bilinear sample + bottleneck relu + layer0 pre terms ----------------
__device__ __forceinline__ float sample_level(const float* __restrict__ pp, int Hh, int Ww,
                                              float gx, float gy, int j) {
    float x = (gx + 1.f) * 0.5f * (float)(Ww - 1);
    float y = (gy + 1.f) * 0.5f * (float)(Hh - 1);
    float x0f = floorf(x), y0f = floorf(y);
    float wx1 = x - x0f, wy1 = y - y0f;
    float wx0 = 1.f - wx1, wy0 = 1.f - wy1;
    int x0 = (int)fminf(fmaxf(x0f, 0.f), (float)(Ww - 1));
    int x1 = (int)fminf(fmaxf(x0f + 1.f, 0.f), (float)(Ww - 1));
    int y0 = (int)fminf(fmaxf(y0f, 0.f), (float)(Hh - 1));
    int y1 = (int)fminf(fmaxf(y0f + 1.f, 0.f), (float)(Hh - 1));
    const float* r00 = pp + (size_t)(y0 * Ww + x0) * 128;
    const float* r01 = pp + (size_t)(y0 * Ww + x1) * 128;
    const float* r10 = pp + (size_t)(y1 * Ww + x0) * 128;
    const float* r11 = pp + (size_t)(y1 * Ww + x1) * 128;
    return wy0 * (wx0 * r00[j] + wx1 * r01[j]) + wy1 * (wx0 * r10[j] + wx1 * r11[j]);
}

__global__ __launch_bounds__(128) void sample_bottleneck_k(
    const float* __restrict__ av, const float* __restrict__ pp1, const float* __restrict__ pp2,
    const float* __restrict__ pp3, const float* __restrict__ pp4, const float* __restrict__ bb,
    const float* __restrict__ verts, const float* __restrict__ encp,
    const float* __restrict__ g0w0, const float* __restrict__ g0w1,
    const float* __restrict__ g0b0, const float* __restrict__ g0b1,
    unsigned short* __restrict__ X, unsigned short* __restrict__ H, int V_, int B_) {
    int n = blockIdx.x, j = threadIdx.x;
    int b = n / V_;
    float gx = av[(size_t)n * 3 + 0];
    float gy = av[(size_t)n * 3 + 1];
    float acc = bb[j];
    acc += sample_level(pp1 + (size_t)b * 3136 * 128, 56, 56, gx, gy, j);
    acc += sample_level(pp2 + (size_t)b * 784 * 128, 28, 28, gx, gy, j);
    acc += sample_level(pp3 + (size_t)b * 196 * 128, 14, 14, gx, gy, j);
    acc += sample_level(pp4 + (size_t)b * 49 * 128, 7, 7, gx, gy, j);
    X[(size_t)n * 128 + j] = f2bf(fmaxf(acc, 0.f));
    float v0 = verts[n * 3 + 0], v1 = verts[n * 3 + 1], v2 = verts[n * 3 + 2];
    float h0 = encp[(0 * B_ + b) * 128 + j] + g0b0[j] + v0 * g0w0[128 * 128 + j] +
               v1 * g0w0[129 * 128 + j] + v2 * g0w0[130 * 128 + j];
    float h1 = encp[(1 * B_ + b) * 128 + j] + g0b1[j] + v0 * g0w1[128 * 128 + j] +
               v1 * g0w1[129 * 128 + j] + v2 * g0w1[130 * 128 + j];
    H[(size_t)n * 256 + j] = f2bf(h0);
    H[(size_t)n * 256 + 128 + j] = f2bf(h1);
}

// ---------------- layer-0 gather: AggX = sum_nb X, AggH = sum_nb h1 (one adj walk) ----------------
__global__ __launch_bounds__(256) void agg0_k(const unsigned short* __restrict__ X,
                                              const unsigned short* __restrict__ H,
                                              const int* __restrict__ rowptr,
                                              const int* __restrict__ adj,
                                              unsigned short* __restrict__ AggX,
                                              unsigned short* __restrict__ AggH, int Nv) {
    int wave = threadIdx.x >> 6, lane = threadIdx.x & 63;
    int n0 = (blockIdx.x * 4 + wave) * 2;
    if (n0 >= Nv) return;
    const unsigned int* Xu = (const unsigned int*)X;
    int r0 = rowptr[n0], r1 = rowptr[n0 + 1], r2 = rowptr[n0 + 2];
    float a0 = 0.f, a1 = 0.f, b0 = 0.f, b1 = 0.f;   // X sums
    float c0 = 0.f, c1 = 0.f, d0 = 0.f, d1 = 0.f;   // h1 sums
    int tA = r0, tB = r1;
    while (tA < r1 || tB < r2) {
        int nbA[8], nbB[8];
        unsigned int wA[8], wB[8], hA[8], hB[8];
#pragma unroll
        for (int q = 0; q < 8; ++q) {
            int ia = tA + q; ia = (ia < r1) ? ia : (r1 - 1); ia = (ia < 0) ? 0 : ia;
            nbA[q] = adj[ia];
            int ib = tB + q; ib = (ib < r2) ? ib : (r2 - 1); ib = (ib < 0) ? 0 : ib;
            nbB[q] = adj[ib];
        }
#pragma unroll
        for (int q = 0; q < 8; ++q) {
            wA[q] = Xu[(size_t)nbA[q] * 64 + lane];
            wB[q] = Xu[(size_t)nbB[q] * 64 + lane];
            hA[q] = *(const unsigned int*)(H + (size_t)nbA[q] * 256 + 128 + 2 * lane);
            hB[q] = *(const unsigned int*)(H + (size_t)nbB[q] * 256 + 128 + 2 * lane);
        }
#pragma unroll
        for (int q = 0; q < 8; ++q) {
            if (tA + q < r1) {
                a0 += bf2f((unsigned short)(wA[q] & 0xffff));
                a1 += bf2f((unsigned short)(wA[q] >> 16));
                c0 += bf2f((unsigned short)(hA[q] & 0xffff));
                c1 += bf2f((unsigned short)(hA[q] >> 16));
            }
            if (tB + q < r2) {
                b0 += bf2f((unsigned short)(wB[q] & 0xffff));
                b1 += bf2f((unsigned short)(wB[q] >> 16));
                d0 += bf2f((unsigned short)(hB[q] & 0xffff));
                d1 += bf2f((unsigned short)(hB[q] >> 16));
            }
        }
        tA += 8;
        tB += 8;
    }
    *(unsigned int*)(AggX + (size_t)n0 * 128 + 2 * lane) =
        (unsigned int)f2bf(a0) | ((unsigned int)f2bf(a1) << 16);
    *(unsigned int*)(AggX + (size_t)(n0 + 1) * 128 + 2 * lane) =
        (unsigned int)f2bf(b0) | ((unsigned int)f2bf(b1) << 16);
    *(unsigned int*)(AggH + (size_t)n0 * 128 + 2 * lane) =
        (unsigned int)f2bf(c0) | ((unsigned int)f2bf(c1) << 16);
    *(unsigned int*)(AggH + (size_t)(n0 + 1) * 128 + 2 * lane) =
        (unsigned int)f2bf(d0) | ((unsigned int)f2bf(d1) << 16);
}

// ---------------- 2-vertex-interleaved gather (layers 1..7) ----------------
__global__ __launch_bounds__(256) void agg_x_k(const unsigned short* __restrict__ X,
                                               const int* __restrict__ rowptr,
                                               const int* __restrict__ adj,
                                               unsigned short* __restrict__ Agg, int Nv) {
    int wave = threadIdx.x >> 6, lane = threadIdx.x & 63;
    int n0 = (blockIdx.x * 4 + wave) * 2;
    if (n0 >= Nv) return;
    const unsigned int* Xu = (const unsigned int*)X;
    int r0 = rowptr[n0], r1 = rowptr[n0 + 1], r2 = rowptr[n0 + 2];
    float a0 = 0.f, a1 = 0.f, b0 = 0.f, b1 = 0.f;
    int tA = r0, tB = r1;
    while (tA < r1 || tB < r2) {
        int nbA[8], nbB[8];
        unsigned int wA[8], wB[8];
#pragma unroll
        for (int q = 0; q < 8; ++q) {
            int ia = tA + q; ia = (ia < r1) ? ia : (r1 - 1); ia = (ia < 0) ? 0 : ia;
            nbA[q] = adj[ia];
            int ib = tB + q; ib = (ib < r2) ? ib : (r2 - 1); ib = (ib < 0) ? 0 : ib;
            nbB[q] = adj[ib];
        }
#pragma unroll
        for (int q = 0; q < 8; ++q) {
            wA[q] = Xu[(size_t)nbA[q] * 64 + lane];
            wB[q] = Xu[(size_t)nbB[q] * 64 + lane];
        }
#pragma unroll
        for (int q = 0; q < 8; ++q) {
            if (tA + q < r1) {
                a0 += bf2f((unsigned short)(wA[q] & 0xffff));
                a1 += bf2f((unsigned short)(wA[q] >> 16));
            }
            if (tB + q < r2) {
                b0 += bf2f((unsigned short)(wB[q] & 0xffff));
                b1 += bf2f((unsigned short)(wB[q] >> 16));
            }
        }
        tA += 8;
        tB += 8;
    }
    unsigned int oA = (unsigned int)f2bf(a0) | ((unsigned int)f2bf(a1) << 16);
    unsigned int oB = (unsigned int)f2bf(b0) | ((unsigned int)f2bf(b1) << 16);
    *(unsigned int*)(Agg + (size_t)n0 * 128 + 2 * lane) = oA;
    *(unsigned int*)(Agg + (size_t)(n0 + 1) * 128 + 2 * lane) = oB;
}

// ---------------- dual-MFMA layer GEMM v3: 128-row x 64-col tiles ----------------
// Layer 0: h0b (Hb base, stride 256) + aggh (gathered h1 sums) supply the affine terms.
__global__ __launch_bounds__(256, 3) void gemm_dual_k(
    const unsigned short* __restrict__ Xin, const unsigned short* __restrict__ Agg,
    const unsigned short* __restrict__ Wt,  // [2][128][128] bf16 n-major (W0, W1)
    const float* __restrict__ b0, const float* __restrict__ b1,
    const unsigned short* __restrict__ h0b, const unsigned short* __restrict__ aggh,
    const int* __restrict__ degv, unsigned short* __restrict__ Xout, int M) {
    __shared__ unsigned short wlds[16384];  // 32 KB weights (stays live both sub-tiles)
    __shared__ unsigned short cs[64 * 72];  // 9 KB epilogue staging
    __shared__ float bS[128];

    int tid = threadIdx.x;
    int m0 = blockIdx.x * 128;
    int yb = blockIdx.y;

    int wave = tid >> 6, lane = tid & 63;
    int row16 = lane & 15;
    int quad = lane >> 4;
    int wrow = wave * 16;

    // prefetch A + deg for sub-tile 0 (overlaps weight staging)
    short8 axT[2][4], agT[2][4];
    int dgT[2][4];
    {
        int g = min(m0 + wrow + row16, M - 1);
#pragma unroll
        for (int ks = 0; ks < 4; ++ks) {
            int koff = ks * 32 + quad * 8;
            axT[0][ks] = *(const short8*)(Xin + (size_t)g * 128 + koff);
            agT[0][ks] = *(const short8*)(Agg + (size_t)g * 128 + koff);
        }
#pragma unroll
        for (int rr = 0; rr < 4; ++rr)
            dgT[0][rr] = degv[min(m0 + wrow + quad * 4 + rr, M - 1)];
    }

    if (tid < 64) {
        bS[tid] = b0 ? b0[yb * 64 + tid] : 0.f;
        bS[64 + tid] = b1 ? b1[yb * 64 + tid] : 0.f;
    }

    const unsigned short* W0h = Wt + (size_t)yb * 64 * 128;
    const unsigned short* W1h = Wt + 16384 + (size_t)yb * 64 * 128;
#pragma unroll
    for (int l = 0; l < 8; ++l) {
        int idx = tid + l * 256;      // 0..2047 16B chunks
        int half = idx >> 10;
        int r = (idx >> 4) & 63;
        int c16 = idx & 15;
        int sw = (c16 ^ (r & 15)) * 8;
        const unsigned short* src = (half ? W1h : W0h) + r * 128 + c16 * 8;
        *(short8*)&wlds[half * 8192 + r * 128 + sw] = *(const short8*)src;
    }
    __syncthreads();

    // prefetch A + deg for sub-tile 1 (overlaps sub-tile-0 MFMA)
    {
        int g = min(m0 + 64 + wrow + row16, M - 1);
#pragma unroll
        for (int ks = 0; ks < 4; ++ks) {
            int koff = ks * 32 + quad * 8;
            axT[1][ks] = *(const short8*)(Xin + (size_t)g * 128 + koff);
            agT[1][ks] = *(const short8*)(Agg + (size_t)g * 128 + koff);
        }
#pragma unroll
        for (int rr = 0; rr < 4; ++rr)
            dgT[1][rr] = degv[min(m0 + 64 + wrow + quad * 4 + rr, M - 1)];
    }

#pragma unroll
    for (int t = 0; t < 2; ++t) {
        int mT = m0 + t * 64;
        floatx4 acc[4];
#pragma unroll
        for (int j = 0; j < 4; j++) acc[j] = (floatx4){0.f, 0.f, 0.f, 0.f};

#pragma unroll
        for (int ks = 0; ks < 4; ++ks) {
            int c = ks * 4 + quad;
#pragma unroll
            for (int nt = 0; nt < 4; ++nt) {
                int wr = nt * 16 + row16;
                short8 bw0 = *(short8*)&wlds[wr * 128 + ((c ^ row16) * 8)];
                short8 bw1 = *(short8*)&wlds[8192 + wr * 128 + ((c ^ row16) * 8)];
                acc[nt] = __builtin_amdgcn_mfma_f32_16x16x32_bf16(axT[t][ks], bw0, acc[nt], 0, 0, 0);
                acc[nt] = __builtin_amdgcn_mfma_f32_16x16x32_bf16(agT[t][ks], bw1, acc[nt], 0, 0, 0);
            }
        }

        // epilogue -> cs (each wave writes its own 16 rows)
#pragma unroll
        for (int nt = 0; nt < 4; ++nt) {
            int colh = nt * 16 + row16;
            int colg = yb * 64 + colh;
            float bc0 = bS[colh];
            float bc1 = bS[64 + colh];
#pragma unroll
            for (int rr = 0; rr < 4; ++rr) {
                int row = wrow + quad * 4 + rr;
                int gm = mT + row;
                float v = acc[nt][rr] + bc0 + (float)dgT[t][rr] * bc1;
                if (h0b && gm < M)
                    v += bf2f(h0b[(size_t)gm * 256 + colg]) +
                         bf2f(aggh[(size_t)gm * 128 + colg]);
                cs[row * 72 + colh] = f2bf(fmaxf(v, 0.f));
            }
        }
        __syncthreads();

        // coalesced copy-out
        {
            int r = tid >> 2;
            int cq = (tid & 3) * 16;
            int gm = mT + r;
            if (gm < M) {
                unsigned short* dst = Xout + (size_t)gm * 128 + yb * 64 + cq;
                *(short8*)dst = *(short8*)&cs[r * 72 + cq];
                *(short8*)(dst + 8) = *(short8*)&cs[r * 72 + cq + 8];
            }
        }
        __syncthreads();  // cs reads done before next sub-tile overwrites
    }
}

// ---------------- head: out = X @ off_w + off_b (wave per vertex) ----------------
__global__ __launch_bounds__(256) void head_k(const unsigned short* __restrict__ X,
                                              const float* __restrict__ off_w,
                                              const float* __restrict__ off_b,
                                              float* __restrict__ out, int Nv) {
    int wave = threadIdx.x >> 6, lane = threadIdx.x & 63;
    int n = blockIdx.x * 4 + wave;
    if (n >= Nv) return;
    unsigned int u = *(const unsigned int*)(X + (size_t)n * 128 + 2 * lane);
    float x0 = bf2f((unsigned short)(u & 0xffff));
    float x1 = bf2f((unsigned short)(u >> 16));
    int c0 = 2 * lane, c1 = 2 * lane + 1;
    float p0 = x0 * off_w[c0 * 3 + 0] + x1 * off_w[c1 * 3 + 0];
    float p1 = x0 * off_w[c0 * 3 + 1] + x1 * off_w[c1 * 3 + 1];
    float p2 = x0 * off_w[c0 * 3 + 2] + x1 * off_w[c1 * 3 + 2];
#pragma unroll
    for (int m = 1; m < 64; m <<= 1) {
        p0 += __shfl_xor(p0, m);
        p1 += __shfl_xor(p1, m);
        p2 += __shfl_xor(p2, m);
    }
    if (lane == 0) {
        out[n * 3 + 0] = p0 + off_b[0];
        out[n * 3 + 1] = p1 + off_b[1];
        out[n * 3 + 2] = p2 + off_b[2];
    }
}

extern "C" void kernel_launch(void* const* d_in, const int* in_sizes, int n_in, void* d_out,
                              int out_size, void* d_ws, size_t ws_size, hipStream_t stream) {
    const float* feat1 = (const float*)d_in[0];
    const float* feat2 = (const float*)d_in[1];
    const float* feat3 = (const float*)d_in[2];
    const float* feat4 = (const float*)d_in[3];
    const float* av = (const float*)d_in[4];
    const float* verts = (const float*)d_in[5];
    const float* image_enc = (const float*)d_in[6];
    const int* edges = (const int*)d_in[7];
    const float* bw = (const float*)d_in[8];
    const float* bb = (const float*)d_in[9];
    const float* g0w0 = (const float*)d_in[10];
    const float* g0b0 = (const float*)d_in[11];
    const float* g0w1 = (const float*)d_in[12];
    const float* g0b1 = (const float*)d_in[13];
    const float* gw0 = (const float*)d_in[14];
    const float* gb0 = (const float*)d_in[15];
    const float* gw1 = (const float*)d_in[16];
    const float* gb1 = (const float*)d_in[17];
    const float* off_w = (const float*)d_in[18];
    const float* off_b = (const float*)d_in[19];

    int B_ = in_sizes[6] / 256;  // 4
    int N_ = in_sizes[5] / 3;    // 40968
    int V_ = N_ / B_;            // 10242
    int E_ = in_sizes[7] / 2;    // 122880

    char* wsb = (char*)d_ws;
    size_t off = 0;
    auto alloc = [&](size_t bytes) -> void* {
        void* p = (void*)(wsb + off);
        off += (bytes + 255) & ~(size_t)255;
        return p;
    };
    int S1 = B_ * 3136 * 128;
    int S2 = B_ * 784 * 128;
    int S3 = B_ * 196 * 128;
    int S4 = B_ * 49 * 128;
    float* pp1 = (float*)alloc((size_t)S1 * 4);
    float* pp2 = (float*)alloc((size_t)S2 * 4);
    float* pp3 = (float*)alloc((size_t)S3 * 4);
    float* pp4 = (float*)alloc((size_t)S4 * 4);
    size_t pp_bytes = off;  // contiguous pp region starts at wsb
    unsigned short* XA = (unsigned short*)alloc((size_t)N_ * 128 * 2);
    unsigned short* XB = (unsigned short*)alloc((size_t)N_ * 128 * 2);
    unsigned short* AggB = (unsigned short*)alloc((size_t)N_ * 128 * 2);
    unsigned short* AggH = (unsigned short*)alloc((size_t)N_ * 128 * 2);
    unsigned short* Hb = (unsigned short*)alloc((size_t)N_ * 256 * 2);
    unsigned short* Wt = (unsigned short*)alloc((size_t)8 * 2 * 128 * 128 * 2);
    unsigned short* bwT = (unsigned short*)alloc((size_t)128 * 3840 * 2);
    float* encp = (float*)alloc((size_t)2 * B_ * 128 * 4);
    int* deg = (int*)alloc((size_t)(N_ + 1) * 4);
    int* rowptr = (int*)alloc((size_t)(N_ + 1) * 4);
    int* cursor = (int*)alloc((size_t)N_ * 4);
    int* excl = (int*)alloc((size_t)N_ * 4);
    int* bsum = (int*)alloc((size_t)64 * 4);
    int* adj = (int*)alloc((size_t)2 * E_ * 4);

    hipMemsetAsync(deg, 0, (N_ + 1) * sizeof(int), stream);
    hipMemsetAsync(wsb, 0, pp_bytes, stream);  // zero pp for atomic accumulation

    // fat prologue: count_deg | prep_w | prep_bwT | enc_proj
    int nE = ceil_div(E_, 256);
    fatpre_k<<<nE + 46 + B_, 256, 0, stream>>>(edges, deg, E_, nE, g0w0, g0w1, gw0, gw1, Wt,
                                               bw, bwT, image_enc, encp, B_);

    // CSR scan + fill
    int nb = ceil_div(N_, 1024);
    scan1_k<<<nb, 1024, 0, stream>>>(deg, excl, bsum, N_);
    scan2_k<<<1, 64, 0, stream>>>(bsum, nb);
    scan3_k<<<nb, 1024, 0, stream>>>(excl, bsum, deg, rowptr, cursor, N_);
    fill_adj_k<<<ceil_div(E_, 256), 256, 0, stream>>>(edges, cursor, adj, E_);

    // pixel projection via MFMA (z-parallel, atomic accumulate into pp)
    int nproj = 49 * B_ * 4 + 13 * B_ * 8 + 4 * B_ * 16 + 1 * B_ * 32;
    proj_all_k<<<nproj, 256, 0, stream>>>(feat1, feat2, feat3, feat4, bwT, pp1, pp2, pp3, pp4,
                                          B_);

    // sample + bottleneck -> XA (bf16 X0); layer0 pre terms (biases baked) -> Hb (bf16)
    sample_bottleneck_k<<<N_, 128, 0, stream>>>(av, pp1, pp2, pp3, pp4, bb, verts, encp, g0w0,
                                                g0w1, g0b0, g0b1, XA, Hb, V_, B_);

    // 2-vertex-per-wave gather grid
    int agrid = ceil_div(N_, 8);

    dim3 ggrid(ceil_div(N_, 128), 2);
    // layer 0: one adj walk gathers X-sums AND h1-sums; epilogue adds h0 + h1-agg
    agg0_k<<<agrid, 256, 0, stream>>>(XA, Hb, rowptr, adj, AggB, AggH, N_);
    gemm_dual_k<<<ggrid, 256, 0, stream>>>(XA, AggB, Wt, nullptr, nullptr, Hb, AggH, deg, XB,
                                           N_);
    unsigned short* Xc = XB;
    unsigned short* Xn = XA;
    for (int i = 0; i < 7; ++i) {
        agg_x_k<<<agrid, 256, 0, stream>>>(Xc, rowptr, adj, AggB, N_);
        gemm_dual_k<<<ggrid, 256, 0, stream>>>(Xc, AggB, Wt + (size_t)(i + 1) * 32768,
                                               gb0 + i * 128, gb1 + i * 128, nullptr, nullptr,
                                               deg, Xn, N_);
        unsigned short* t = Xc;
        Xc = Xn;
        Xn = t;
    }
    head_k<<<ceil_div(N_, 4), 256, 0, stream>>>(Xc, off_w, off_b, (float*)d_out, N_);
}

// Round 7
// 428.439 us; speedup vs baseline: 1.7276x; 1.1005x over previous
//
#include <hip/hip_runtime.h>

static inline int ceil_div(int a, int b) { return (a + b - 1) / b; }

typedef __attribute__((ext_vector_type(8))) short short8;
typedef __attribute__((ext_vector_type(4))) float floatx4;

__device__ __forceinline__ unsigned short f2bf(float f) {
    unsigned int u = __float_as_uint(f);
    unsigned int r = (u + 0x7fffu + ((u >> 16) & 1u)) >> 16;
    return (unsigned short)r;
}
__device__ __forceinline__ float bf2f(unsigned short h) {
    return __uint_as_float(((unsigned int)h) << 16);
}

// ---------------- CSR scan ----------------
__global__ __launch_bounds__(1024) void scan1_k(const int* __restrict__ deg,
                                                int* __restrict__ excl,
                                                int* __restrict__ bsum, int Nv) {
    __shared__ int s[1024];
    int tid = threadIdx.x;
    int i = blockIdx.x * 1024 + tid;
    int v = (i < Nv) ? deg[i] : 0;
    s[tid] = v;
    __syncthreads();
    for (int off = 1; off < 1024; off <<= 1) {
        int t = (tid >= off) ? s[tid - off] : 0;
        __syncthreads();
        if (tid >= off) s[tid] += t;
        __syncthreads();
    }
    if (i < Nv) excl[i] = s[tid] - v;
    if (tid == 1023) bsum[blockIdx.x] = s[1023];
}

__global__ __launch_bounds__(64) void scan2_k(int* __restrict__ bsum, int nb) {
    __shared__ int s[64];
    int tid = threadIdx.x;
    int v = (tid < nb) ? bsum[tid] : 0;
    s[tid] = v;
    __syncthreads();
    for (int off = 1; off < 64; off <<= 1) {
        int t = (tid >= off) ? s[tid - off] : 0;
        __syncthreads();
        if (tid >= off) s[tid] += t;
        __syncthreads();
    }
    if (tid < nb) bsum[tid] = s[tid] - v;
}

__global__ __launch_bounds__(1024) void scan3_k(const int* __restrict__ excl,
                                                const int* __restrict__ bsum,
                                                const int* __restrict__ deg,
                                                int* __restrict__ rowptr,
                                                int* __restrict__ cursor, int Nv) {
    int i = blockIdx.x * 1024 + threadIdx.x;
    if (i < Nv) {
        int val = excl[i] + bsum[blockIdx.x];
        rowptr[i] = val;
        cursor[i] = val;
        if (i == Nv - 1) rowptr[Nv] = val + deg[i];
    }
}

__global__ __launch_bounds__(256) void fill_adj_k(const int* __restrict__ edges,
                                                  int* __restrict__ cursor,
                                                  int* __restrict__ adj, int E) {
    int e = blockIdx.x * blockDim.x + threadIdx.x;
    if (e < E) {
        int a = edges[2 * e], b = edges[2 * e + 1];
        adj[atomicAdd(&cursor[a], 1)] = b;
        adj[atomicAdd(&cursor[b], 1)] = a;
    }
}

// ---------------- fat prologue: count_deg | prep_w | prep_bwT | enc_proj ----------------
__global__ __launch_bounds__(256) void fatpre_k(const int* __restrict__ edges,
                                                int* __restrict__ deg, int E, int nE,
                                                const float* __restrict__ g0w0,
                                                const float* __restrict__ g0w1,
                                                const float* __restrict__ gw0,
                                                const float* __restrict__ gw1,
                                                unsigned short* __restrict__ Wt,
                                                const float* __restrict__ bw,
                                                unsigned short* __restrict__ bwT,
                                                const float* __restrict__ enc,
                                                float* __restrict__ encp, int B_) {
    int bid = blockIdx.x;
    int tid = threadIdx.x;
    if (bid < nE) {
        int e = bid * 256 + tid;
        if (e < E) {
            atomicAdd(&deg[edges[2 * e]], 1);
            atomicAdd(&deg[edges[2 * e + 1]], 1);
        }
    } else if (bid < nE + 16) {
        int lh = bid - nE;
        int l = lh >> 1, h = lh & 1;
        const float* src;
        if (l == 0) src = h ? g0w1 : g0w0;
        else src = (h ? gw1 : gw0) + (size_t)(l - 1) * 16384;
        unsigned short* dst = Wt + (size_t)lh * 16384;
        for (int idx = tid; idx < 16384; idx += 256) {
            int n = idx >> 7, k = idx & 127;
            dst[n * 128 + k] = f2bf(src[k * 128 + n]);
        }
    } else if (bid < nE + 46) {
        // bottleneck weight transpose+cast: bwT[n][k] = bf16(bw[k][n])
        int blk = bid - nE - 16;  // 0..29
        for (int idx = tid; idx < 16384; idx += 256) {
            int n = idx >> 7, kk = idx & 127;
            bwT[(size_t)n * 3840 + blk * 128 + kk] =
                f2bf(bw[(size_t)(blk * 128 + kk) * 128 + n]);
        }
    } else {
        int b = bid - nE - 46;
        int sH = tid >> 7;
        int j = tid & 127;
        const float* w = sH ? g0w1 : g0w0;
        const float* eb = enc + b * 256;
        float acc = 0.f;
        for (int c = 0; c < 256; ++c) acc = fmaf(eb[c], w[(131 + c) * 128 + j], acc);
        encp[(sH * B_ + b) * 128 + j] = acc;
    }
}

// ---------------- pixel projection via MFMA (K=128 per block, atomic accumulate) ----------------
// Each block accumulates TWO 64-wide K chunks in registers before one atomic
// flush -> half the atomic write-through traffic and half the blocks vs K=64.
__global__ __launch_bounds__(256) void proj_all_k(
    const float* __restrict__ fm1, const float* __restrict__ fm2,
    const float* __restrict__ fm3, const float* __restrict__ fm4,
    const unsigned short* __restrict__ bwT, float* __restrict__ o1, float* __restrict__ o2,
    float* __restrict__ o3, float* __restrict__ o4, int B_) {
    __shared__ unsigned short wlds[8192];  // 16 KB: [128 n][64 k] bf16, XOR-swizzled

    int tid = threadIdx.x;
    int n1 = 49 * B_ * 2, n2 = 13 * B_ * 4, n3 = 4 * B_ * 8;
    int bid = blockIdx.x;
    const float* fm;
    float* op;
    int C, HW, PT, idx, koff;
    if (bid < n1) {
        fm = fm1; op = o1; C = 256; HW = 3136; PT = 49; idx = bid; koff = 0;
    } else if (bid < n1 + n2) {
        fm = fm2; op = o2; C = 512; HW = 784; PT = 13; idx = bid - n1; koff = 256;
    } else if (bid < n1 + n2 + n3) {
        fm = fm3; op = o3; C = 1024; HW = 196; PT = 4; idx = bid - n1 - n2; koff = 768;
    } else {
        fm = fm4; op = o4; C = 2048; HW = 49; PT = 1; idx = bid - n1 - n2 - n3; koff = 1792;
    }
    int pt = idx % PT;
    int r2 = idx / PT;
    int b = r2 % B_;
    int zz = r2 / B_;
    int p0 = pt * 64;
    const float* fmb = fm + (size_t)b * C * HW;
    int kcf0 = zz * 128;  // this block's 128-wide channel window

    int wave = tid >> 6, lane = tid & 63;
    int row16 = lane & 15, quad = lane >> 4;
    int p = p0 + wave * 16 + row16;
    bool pok = (p < HW);
    int pc = pok ? p : 0;

    floatx4 acc[8];
#pragma unroll
    for (int j = 0; j < 8; ++j) acc[j] = (floatx4){0.f, 0.f, 0.f, 0.f};

#pragma unroll
    for (int zz2 = 0; zz2 < 2; ++zz2) {
        int kcf = kcf0 + zz2 * 64;
        int kcw = koff + kcf;
        if (zz2) __syncthreads();  // protect previous chunk's wlds reads
        // stage W^T tile [128 n][64 k] bf16, swizzled
#pragma unroll
        for (int l = 0; l < 4; ++l) {
            int i2 = tid + l * 256;  // 0..1023
            int n = i2 >> 3, c16 = i2 & 7;
            *(short8*)&wlds[n * 64 + ((c16 ^ (n & 7)) * 8)] =
                *(const short8*)(bwT + (size_t)n * 3840 + kcw + c16 * 8);
        }
        short8 ax[2];
#pragma unroll
        for (int ks = 0; ks < 2; ++ks) {
#pragma unroll
            for (int j = 0; j < 8; ++j) {
                float v = pok ? fmb[(size_t)(kcf + ks * 32 + quad * 8 + j) * HW + pc] : 0.f;
                ax[ks][j] = (short)f2bf(v);
            }
        }
        __syncthreads();
#pragma unroll
        for (int ks = 0; ks < 2; ++ks) {
            int c = ks * 4 + quad;
#pragma unroll
            for (int nt = 0; nt < 8; ++nt) {
                int wr = nt * 16 + row16;
                short8 bwf = *(short8*)&wlds[wr * 64 + ((c ^ (wr & 7)) * 8)];
                acc[nt] =
                    __builtin_amdgcn_mfma_f32_16x16x32_bf16(ax[ks], bwf, acc[nt], 0, 0, 0);
            }
        }
    }

    float* obase = op + (size_t)b * HW * 128;
#pragma unroll
    for (int nt = 0; nt < 8; ++nt) {
        int colg = nt * 16 + row16;
#pragma unroll
        for (int rr = 0; rr < 4; ++rr) {
            int pr = p0 + wave * 16 + quad * 4 + rr;
            if (pr < HW) atomicAdd(&obase[(size_t)pr * 128 + colg], acc[nt][rr]);
        }
    }
}

// ---------------- bilinear sample + bottleneck relu + layer0 pre terms ----------------
__device__ __forceinline__ float sample_level(const float* __restrict__ pp, int Hh, int Ww,
                                              float gx, float gy, int j) {
    float x = (gx + 1.f) * 0.5f * (float)(Ww - 1);
    float y = (gy + 1.f) * 0.5f * (float)(Hh - 1);
    float x0f = floorf(x), y0f = floorf(y);
    float wx1 = x - x0f, wy1 = y - y0f;
    float wx0 = 1.f - wx1, wy0 = 1.f - wy1;
    int x0 = (int)fminf(fmaxf(x0f, 0.f), (float)(Ww - 1));
    int x1 = (int)fminf(fmaxf(x0f + 1.f, 0.f), (float)(Ww - 1));
    int y0 = (int)fminf(fmaxf(y0f, 0.f), (float)(Hh - 1));
    int y1 = (int)fminf(fmaxf(y0f + 1.f, 0.f), (float)(Hh - 1));
    const float* r00 = pp + (size_t)(y0 * Ww + x0) * 128;
    const float* r01 = pp + (size_t)(y0 * Ww + x1) * 128;
    const float* r10 = pp + (size_t)(y1 * Ww + x0) * 128;
    const float* r11 = pp + (size_t)(y1 * Ww + x1) * 128;
    return wy0 * (wx0 * r00[j] + wx1 * r01[j]) + wy1 * (wx0 * r10[j] + wx1 * r11[j]);
}

__global__ __launch_bounds__(128) void sample_bottleneck_k(
    const float* __restrict__ av, const float* __restrict__ pp1, const float* __restrict__ pp2,
    const float* __restrict__ pp3, const float* __restrict__ pp4, const float* __restrict__ bb,
    const float* __restrict__ verts, const float* __restrict__ encp,
    const float* __restrict__ g0w0, const float* __restrict__ g0w1,
    const float* __restrict__ g0b0, const float* __restrict__ g0b1,
    unsigned short* __restrict__ X, unsigned short* __restrict__ H, int V_, int B_) {
    int n = blockIdx.x, j = threadIdx.x;
    int b = n / V_;
    float gx = av[(size_t)n * 3 + 0];
    float gy = av[(size_t)n * 3 + 1];
    float acc = bb[j];
    acc += sample_level(pp1 + (size_t)b * 3136 * 128, 56, 56, gx, gy, j);
    acc += sample_level(pp2 + (size_t)b * 784 * 128, 28, 28, gx, gy, j);
    acc += sample_level(pp3 + (size_t)b * 196 * 128, 14, 14, gx, gy, j);
    acc += sample_level(pp4 + (size_t)b * 49 * 128, 7, 7, gx, gy, j);
    X[(size_t)n * 128 + j] = f2bf(fmaxf(acc, 0.f));
    float v0 = verts[n * 3 + 0], v1 = verts[n * 3 + 1], v2 = verts[n * 3 + 2];
    float h0 = encp[(0 * B_ + b) * 128 + j] + g0b0[j] + v0 * g0w0[128 * 128 + j] +
               v1 * g0w0[129 * 128 + j] + v2 * g0w0[130 * 128 + j];
    float h1 = encp[(1 * B_ + b) * 128 + j] + g0b1[j] + v0 * g0w1[128 * 128 + j] +
               v1 * g0w1[129 * 128 + j] + v2 * g0w1[130 * 128 + j];
    H[(size_t)n * 256 + j] = f2bf(h0);
    H[(size_t)n * 256 + 128 + j] = f2bf(h1);
}

// ---------------- layer-0 gather: AggX = sum_nb X, AggH = sum_nb h1 (one adj walk) ----------------
__global__ __launch_bounds__(256) void agg0_k(const unsigned short* __restrict__ X,
                                              const unsigned short* __restrict__ H,
                                              const int* __restrict__ rowptr,
                                              const int* __restrict__ adj,
                                              unsigned short* __restrict__ AggX,
                                              unsigned short* __restrict__ AggH, int Nv) {
    int wave = threadIdx.x >> 6, lane = threadIdx.x & 63;
    int n0 = (blockIdx.x * 4 + wave) * 2;
    if (n0 >= Nv) return;
    const unsigned int* Xu = (const unsigned int*)X;
    int r0 = rowptr[n0], r1 = rowptr[n0 + 1], r2 = rowptr[n0 + 2];
    float a0 = 0.f, a1 = 0.f, b0 = 0.f, b1 = 0.f;   // X sums
    float c0 = 0.f, c1 = 0.f, d0 = 0.f, d1 = 0.f;   // h1 sums
    int tA = r0, tB = r1;
    while (tA < r1 || tB < r2) {
        int nbA[8], nbB[8];
        unsigned int wA[8], wB[8], hA[8], hB[8];
#pragma unroll
        for (int q = 0; q < 8; ++q) {
            int ia = tA + q; ia = (ia < r1) ? ia : (r1 - 1); ia = (ia < 0) ? 0 : ia;
            nbA[q] = adj[ia];
            int ib = tB + q; ib = (ib < r2) ? ib : (r2 - 1); ib = (ib < 0) ? 0 : ib;
            nbB[q] = adj[ib];
        }
#pragma unroll
        for (int q = 0; q < 8; ++q) {
            wA[q] = Xu[(size_t)nbA[q] * 64 + lane];
            wB[q] = Xu[(size_t)nbB[q] * 64 + lane];
            hA[q] = *(const unsigned int*)(H + (size_t)nbA[q] * 256 + 128 + 2 * lane);
            hB[q] = *(const unsigned int*)(H + (size_t)nbB[q] * 256 + 128 + 2 * lane);
        }
#pragma unroll
        for (int q = 0; q < 8; ++q) {
            if (tA + q < r1) {
                a0 += bf2f((unsigned short)(wA[q] & 0xffff));
                a1 += bf2f((unsigned short)(wA[q] >> 16));
                c0 += bf2f((unsigned short)(hA[q] & 0xffff));
                c1 += bf2f((unsigned short)(hA[q] >> 16));
            }
            if (tB + q < r2) {
                b0 += bf2f((unsigned short)(wB[q] & 0xffff));
                b1 += bf2f((unsigned short)(wB[q] >> 16));
                d0 += bf2f((unsigned short)(hB[q] & 0xffff));
                d1 += bf2f((unsigned short)(hB[q] >> 16));
            }
        }
        tA += 8;
        tB += 8;
    }
    *(unsigned int*)(AggX + (size_t)n0 * 128 + 2 * lane) =
        (unsigned int)f2bf(a0) | ((unsigned int)f2bf(a1) << 16);
    *(unsigned int*)(AggX + (size_t)(n0 + 1) * 128 + 2 * lane) =
        (unsigned int)f2bf(b0) | ((unsigned int)f2bf(b1) << 16);
    *(unsigned int*)(AggH + (size_t)n0 * 128 + 2 * lane) =
        (unsigned int)f2bf(c0) | ((unsigned int)f2bf(c1) << 16);
    *(unsigned int*)(AggH + (size_t)(n0 + 1) * 128 + 2 * lane) =
        (unsigned int)f2bf(d0) | ((unsigned int)f2bf(d1) << 16);
}

// ---------------- gather v2: 4 vertices/wave, 16-lane groups, short8 lane loads ----------
// Each VMEM instruction fetches FOUR random 256B rows (1 KB): group g (lanes
// g*16..g*16+15) owns vertex n0+g; lane c of the group loads 16B of the row.
// Quarters the gather request/instruction count; 32 rows in flight per wave.
__global__ __launch_bounds__(256) void agg_x_k(const unsigned short* __restrict__ X,
                                               const int* __restrict__ rowptr,
                                               const int* __restrict__ adj,
                                               unsigned short* __restrict__ Agg, int Nv,
                                               int Etot) {
    int wave = threadIdx.x >> 6, lane = threadIdx.x & 63;
    int n0 = (blockIdx.x * 4 + wave) * 4;
    if (n0 >= Nv) return;
    int g = lane >> 4, c = lane & 15;
    int rp = rowptr[min(n0 + (lane & 7), Nv)];  // lanes 0..4 meaningful
    int sg = __shfl(rp, g);
    int eg = __shfl(rp, g + 1);
    int m = eg - sg;
    m = max(m, __shfl_xor(m, 16));
    m = max(m, __shfl_xor(m, 32));  // max degree over the 4 groups

    float acc[8];
#pragma unroll
    for (int j = 0; j < 8; ++j) acc[j] = 0.f;

    for (int it = 0; it < m; it += 8) {
        int t = sg + it + (lane & 7);
        int adjv = adj[min(t, Etot - 1)];
        short8 buf[8];
#pragma unroll
        for (int q = 0; q < 8; ++q) {
            int nbq = __shfl(adjv, (lane & 48) + q);  // group base lane + q
            buf[q] = *(const short8*)(X + (size_t)nbq * 128 + c * 8);
        }
#pragma unroll
        for (int q = 0; q < 8; ++q) {
            bool ok = (sg + it + q < eg);
#pragma unroll
            for (int j = 0; j < 8; ++j) {
                float v = bf2f((unsigned short)buf[q][j]);
                acc[j] += ok ? v : 0.f;
            }
        }
    }

    if (n0 + g < Nv) {
        short8 o;
#pragma unroll
        for (int j = 0; j < 8; ++j) o[j] = (short)f2bf(acc[j]);
        *(short8*)(Agg + (size_t)(n0 + g) * 128 + c * 8) = o;
    }
}

// ---------------- dual-MFMA layer GEMM v3: 128-row x 64-col tiles ----------------
// Layer 0: h0b (Hb base, stride 256) + aggh (gathered h1 sums) supply the affine terms.
__global__ __launch_bounds__(256, 3) void gemm_dual_k(
    const unsigned short* __restrict__ Xin, const unsigned short* __restrict__ Agg,
    const unsigned short* __restrict__ Wt,  // [2][128][128] bf16 n-major (W0, W1)
    const float* __restrict__ b0, const float* __restrict__ b1,
    const unsigned short* __restrict__ h0b, const unsigned short* __restrict__ aggh,
    const int* __restrict__ degv, unsigned short* __restrict__ Xout, int M) {
    __shared__ unsigned short wlds[16384];  // 32 KB weights (stays live both sub-tiles)
    __shared__ unsigned short cs[64 * 72];  // 9 KB epilogue staging
    __shared__ float bS[128];

    int tid = threadIdx.x;
    int m0 = blockIdx.x * 128;
    int yb = blockIdx.y;

    int wave = tid >> 6, lane = tid & 63;
    int row16 = lane & 15;
    int quad = lane >> 4;
    int wrow = wave * 16;

    // prefetch A + deg for sub-tile 0 (overlaps weight staging)
    short8 axT[2][4], agT[2][4];
    int dgT[2][4];
    {
        int g = min(m0 + wrow + row16, M - 1);
#pragma unroll
        for (int ks = 0; ks < 4; ++ks) {
            int koff = ks * 32 + quad * 8;
            axT[0][ks] = *(const short8*)(Xin + (size_t)g * 128 + koff);
            agT[0][ks] = *(const short8*)(Agg + (size_t)g * 128 + koff);
        }
#pragma unroll
        for (int rr = 0; rr < 4; ++rr)
            dgT[0][rr] = degv[min(m0 + wrow + quad * 4 + rr, M - 1)];
    }

    if (tid < 64) {
        bS[tid] = b0 ? b0[yb * 64 + tid] : 0.f;
        bS[64 + tid] = b1 ? b1[yb * 64 + tid] : 0.f;
    }

    const unsigned short* W0h = Wt + (size_t)yb * 64 * 128;
    const unsigned short* W1h = Wt + 16384 + (size_t)yb * 64 * 128;
#pragma unroll
    for (int l = 0; l < 8; ++l) {
        int idx = tid + l * 256;      // 0..2047 16B chunks
        int half = idx >> 10;
        int r = (idx >> 4) & 63;
        int c16 = idx & 15;
        int sw = (c16 ^ (r & 15)) * 8;
        const unsigned short* src = (half ? W1h : W0h) + r * 128 + c16 * 8;
        *(short8*)&wlds[half * 8192 + r * 128 + sw] = *(const short8*)src;
    }
    __syncthreads();

    // prefetch A + deg for sub-tile 1 (overlaps sub-tile-0 MFMA)
    {
        int g = min(m0 + 64 + wrow + row16, M - 1);
#pragma unroll
        for (int ks = 0; ks < 4; ++ks) {
            int koff = ks * 32 + quad * 8;
            axT[1][ks] = *(const short8*)(Xin + (size_t)g * 128 + koff);
            agT[1][ks] = *(const short8*)(Agg + (size_t)g * 128 + koff);
        }
#pragma unroll
        for (int rr = 0; rr < 4; ++rr)
            dgT[1][rr] = degv[min(m0 + 64 + wrow + quad * 4 + rr, M - 1)];
    }

#pragma unroll
    for (int t = 0; t < 2; ++t) {
        int mT = m0 + t * 64;
        floatx4 acc[4];
#pragma unroll
        for (int j = 0; j < 4; j++) acc[j] = (floatx4){0.f, 0.f, 0.f, 0.f};

#pragma unroll
        for (int ks = 0; ks < 4; ++ks) {
            int c = ks * 4 + quad;
#pragma unroll
            for (int nt = 0; nt < 4; ++nt) {
                int wr = nt * 16 + row16;
                short8 bw0 = *(short8*)&wlds[wr * 128 + ((c ^ row16) * 8)];
                short8 bw1 = *(short8*)&wlds[8192 + wr * 128 + ((c ^ row16) * 8)];
                acc[nt] = __builtin_amdgcn_mfma_f32_16x16x32_bf16(axT[t][ks], bw0, acc[nt], 0, 0, 0);
                acc[nt] = __builtin_amdgcn_mfma_f32_16x16x32_bf16(agT[t][ks], bw1, acc[nt], 0, 0, 0);
            }
        }

        // epilogue -> cs (each wave writes its own 16 rows)
#pragma unroll
        for (int nt = 0; nt < 4; ++nt) {
            int colh = nt * 16 + row16;
            int colg = yb * 64 + colh;
            float bc0 = bS[colh];
            float bc1 = bS[64 + colh];
#pragma unroll
            for (int rr = 0; rr < 4; ++rr) {
                int row = wrow + quad * 4 + rr;
                int gm = mT + row;
                float v = acc[nt][rr] + bc0 + (float)dgT[t][rr] * bc1;
                if (h0b && gm < M)
                    v += bf2f(h0b[(size_t)gm * 256 + colg]) +
                         bf2f(aggh[(size_t)gm * 128 + colg]);
                cs[row * 72 + colh] = f2bf(fmaxf(v, 0.f));
            }
        }
        __syncthreads();

        // coalesced copy-out
        {
            int r = tid >> 2;
            int cq = (tid & 3) * 16;
            int gm = mT + r;
            if (gm < M) {
                unsigned short* dst = Xout + (size_t)gm * 128 + yb * 64 + cq;
                *(short8*)dst = *(short8*)&cs[r * 72 + cq];
                *(short8*)(dst + 8) = *(short8*)&cs[r * 72 + cq + 8];
            }
        }
        __syncthreads();  // cs reads done before next sub-tile overwrites
    }
}

// ---------------- head: out = X @ off_w + off_b (wave per vertex) ----------------
__global__ __launch_bounds__(256) void head_k(const unsigned short* __restrict__ X,
                                              const float* __restrict__ off_w,
                                              const float* __restrict__ off_b,
                                              float* __restrict__ out, int Nv) {
    int wave = threadIdx.x >> 6, lane = threadIdx.x & 63;
    int n = blockIdx.x * 4 + wave;
    if (n >= Nv) return;
    unsigned int u = *(const unsigned int*)(X + (size_t)n * 128 + 2 * lane);
    float x0 = bf2f((unsigned short)(u & 0xffff));
    float x1 = bf2f((unsigned short)(u >> 16));
    int c0 = 2 * lane, c1 = 2 * lane + 1;
    float p0 = x0 * off_w[c0 * 3 + 0] + x1 * off_w[c1 * 3 + 0];
    float p1 = x0 * off_w[c0 * 3 + 1] + x1 * off_w[c1 * 3 + 1];
    float p2 = x0 * off_w[c0 * 3 + 2] + x1 * off_w[c1 * 3 + 2];
#pragma unroll
    for (int m = 1; m < 64; m <<= 1) {
        p0 += __shfl_xor(p0, m);
        p1 += __shfl_xor(p1, m);
        p2 += __shfl_xor(p2, m);
    }
    if (lane == 0) {
        out[n * 3 + 0] = p0 + off_b[0];
        out[n * 3 + 1] = p1 + off_b[1];
        out[n * 3 + 2] = p2 + off_b[2];
    }
}

extern "C" void kernel_launch(void* const* d_in, const int* in_sizes, int n_in, void* d_out,
                              int out_size, void* d_ws, size_t ws_size, hipStream_t stream) {
    const float* feat1 = (const float*)d_in[0];
    const float* feat2 = (const float*)d_in[1];
    const float* feat3 = (const float*)d_in[2];
    const float* feat4 = (const float*)d_in[3];
    const float* av = (const float*)d_in[4];
    const float* verts = (const float*)d_in[5];
    const float* image_enc = (const float*)d_in[6];
    const int* edges = (const int*)d_in[7];
    const float* bw = (const float*)d_in[8];
    const float* bb = (const float*)d_in[9];
    const float* g0w0 = (const float*)d_in[10];
    const float* g0b0 = (const float*)d_in[11];
    const float* g0w1 = (const float*)d_in[12];
    const float* g0b1 = (const float*)d_in[13];
    const float* gw0 = (const float*)d_in[14];
    const float* gb0 = (const float*)d_in[15];
    const float* gw1 = (const float*)d_in[16];
    const float* gb1 = (const float*)d_in[17];
    const float* off_w = (const float*)d_in[18];
    const float* off_b = (const float*)d_in[19];

    int B_ = in_sizes[6] / 256;  // 4
    int N_ = in_sizes[5] / 3;    // 40968
    int V_ = N_ / B_;            // 10242
    int E_ = in_sizes[7] / 2;    // 122880

    char* wsb = (char*)d_ws;
    size_t off = 0;
    auto alloc = [&](size_t bytes) -> void* {
        void* p = (void*)(wsb + off);
        off += (bytes + 255) & ~(size_t)255;
        return p;
    };
    int S1 = B_ * 3136 * 128;
    int S2 = B_ * 784 * 128;
    int S3 = B_ * 196 * 128;
    int S4 = B_ * 49 * 128;
    float* pp1 = (float*)alloc((size_t)S1 * 4);
    float* pp2 = (float*)alloc((size_t)S2 * 4);
    float* pp3 = (float*)alloc((size_t)S3 * 4);
    float* pp4 = (float*)alloc((size_t)S4 * 4);
    size_t pp_bytes = off;  // contiguous pp region starts at wsb
    unsigned short* XA = (unsigned short*)alloc((size_t)N_ * 128 * 2);
    unsigned short* XB = (unsigned short*)alloc((size_t)N_ * 128 * 2);
    unsigned short* AggB = (unsigned short*)alloc((size_t)N_ * 128 * 2);
    unsigned short* AggH = (unsigned short*)alloc((size_t)N_ * 128 * 2);
    unsigned short* Hb = (unsigned short*)alloc((size_t)N_ * 256 * 2);
    unsigned short* Wt = (unsigned short*)alloc((size_t)8 * 2 * 128 * 128 * 2);
    unsigned short* bwT = (unsigned short*)alloc((size_t)128 * 3840 * 2);
    float* encp = (float*)alloc((size_t)2 * B_ * 128 * 4);
    int* deg = (int*)alloc((size_t)(N_ + 1) * 4);
    int* rowptr = (int*)alloc((size_t)(N_ + 1) * 4);
    int* cursor = (int*)alloc((size_t)N_ * 4);
    int* excl = (int*)alloc((size_t)N_ * 4);
    int* bsum = (int*)alloc((size_t)64 * 4);
    int* adj = (int*)alloc((size_t)2 * E_ * 4);

    hipMemsetAsync(deg, 0, (N_ + 1) * sizeof(int), stream);
    hipMemsetAsync(wsb, 0, pp_bytes, stream);  // zero pp for atomic accumulation

    // fat prologue: count_deg | prep_w | prep_bwT | enc_proj
    int nE = ceil_div(E_, 256);
    fatpre_k<<<nE + 46 + B_, 256, 0, stream>>>(edges, deg, E_, nE, g0w0, g0w1, gw0, gw1, Wt,
                                               bw, bwT, image_enc, encp, B_);

    // CSR scan + fill
    int nb = ceil_div(N_, 1024);
    scan1_k<<<nb, 1024, 0, stream>>>(deg, excl, bsum, N_);
    scan2_k<<<1, 64, 0, stream>>>(bsum, nb);
    scan3_k<<<nb, 1024, 0, stream>>>(excl, bsum, deg, rowptr, cursor, N_);
    fill_adj_k<<<ceil_div(E_, 256), 256, 0, stream>>>(edges, cursor, adj, E_);

    // pixel projection via MFMA (K=128 per block, atomic accumulate into pp)
    int nproj = 49 * B_ * 2 + 13 * B_ * 4 + 4 * B_ * 8 + 1 * B_ * 16;
    proj_all_k<<<nproj, 256, 0, stream>>>(feat1, feat2, feat3, feat4, bwT, pp1, pp2, pp3, pp4,
                                          B_);

    // sample + bottleneck -> XA (bf16 X0); layer0 pre terms (biases baked) -> Hb (bf16)
    sample_bottleneck_k<<<N_, 128, 0, stream>>>(av, pp1, pp2, pp3, pp4, bb, verts, encp, g0w0,
                                                g0w1, g0b0, g0b1, XA, Hb, V_, B_);

    dim3 ggrid(ceil_div(N_, 128), 2);
    // layer 0: one adj walk gathers X-sums AND h1-sums; epilogue adds h0 + h1-agg
    agg0_k<<<ceil_div(N_, 8), 256, 0, stream>>>(XA, Hb, rowptr, adj, AggB, AggH, N_);
    gemm_dual_k<<<ggrid, 256, 0, stream>>>(XA, AggB, Wt, nullptr, nullptr, Hb, AggH, deg, XB,
                                           N_);
    unsigned short* Xc = XB;
    unsigned short* Xn = XA;
    int agrid4 = ceil_div(N_, 16);
    for (int i = 0; i < 7; ++i) {
        agg_x_k<<<agrid4, 256, 0, stream>>>(Xc, rowptr, adj, AggB, N_, 2 * E_);
        gemm_dual_k<<<ggrid, 256, 0, stream>>>(Xc, AggB, Wt + (size_t)(i + 1) * 32768,
                                               gb0 + i * 128, gb1 + i * 128, nullptr, nullptr,
                                               deg, Xn, N_);
        unsigned short* t = Xc;
        Xc = Xn;
        Xn = t;
    }
    head_k<<<ceil_div(N_, 4), 256, 0, stream>>>(Xc, off_w, off_b, (float*)d_out, N_);
}